// Round 11
// baseline (2351.150 us; speedup 1.0000x reference)
//
#include <hip/hip_runtime.h>
#include <hip/hip_bf16.h>
#include <cstdint>

#define T_TOK 4096
#define NEXP  32
#define TOPK  4
#define CAP   512
#define H     1024
#define E     1024
#define NH    4
#define HD    256
#define MAXROWS (T_TOK*TOPK)   // 16384

typedef __attribute__((ext_vector_type(4))) float f32x4;
typedef __attribute__((ext_vector_type(8))) short short8;

__device__ __forceinline__ float bf2f(ushort u) {
  return __uint_as_float(((uint)u) << 16);
}
__device__ __forceinline__ ushort f2bf(float f) {
  uint u = __float_as_uint(f);
  uint r = (u + 0x7fffu + ((u >> 16) & 1u)) >> 16;
  return (ushort)r;
}
__device__ __forceinline__ void split2(float v, ushort& h, ushort& l) {
  h = f2bf(v);
  l = f2bf(v - bf2f(h));
}
__device__ __forceinline__ void gload16(const void* g, void* l) {
  __builtin_amdgcn_global_load_lds((const __attribute__((address_space(1))) void*)g,
                                   (__attribute__((address_space(3))) void*)l, 16, 0, 0);
}

// packed f32 pair -> (hi bf16x2, lo bf16x2); RNE, bit-identical to split2
#define CVTPK(F0, F1, HP, LP) do { \
  asm("v_cvt_pk_bf16_f32 %0, %1, %2" : "=v"(HP) : "v"(F0), "v"(F1)); \
  float _h0 = __uint_as_float((HP) << 16); \
  float _h1 = __uint_as_float((HP) & 0xffff0000u); \
  float _l0 = (F0) - _h0, _l1 = (F1) - _h1; \
  asm("v_cvt_pk_bf16_f32 %0, %1, %2" : "=v"(LP) : "v"(_l0), "v"(_l1)); \
} while (0)

#define CVTPK_HI(F0, F1, HP) \
  asm("v_cvt_pk_bf16_f32 %0, %1, %2" : "=v"(HP) : "v"(F0), "v"(F1))

// ---------------- K1: router ----------------
__global__ __launch_bounds__(256) void k_router(const float* __restrict__ x, const float* __restrict__ rw,
                                                int* __restrict__ topi, float* __restrict__ topw) {
  int t = blockIdx.x;
  __shared__ float4 xs[256];
  __shared__ float lg[NEXP];
  const float4* xr = (const float4*)(x + (size_t)t * H);
  xs[threadIdx.x] = xr[threadIdx.x];
  __syncthreads();
  int g = threadIdx.x >> 3, s = threadIdx.x & 7;
  const float4* wr = (const float4*)(rw + (size_t)g * H);
  float acc = 0.f;
  for (int j = s; j < 256; j += 8) {
    float4 a = xs[j], b = wr[j];
    acc += a.x * b.x + a.y * b.y + a.z * b.z + a.w * b.w;
  }
  acc += __shfl_xor(acc, 1);
  acc += __shfl_xor(acc, 2);
  acc += __shfl_xor(acc, 4);
  if (s == 0) lg[g] = acc;
  __syncthreads();
  if (threadIdx.x == 0) {
    float mx = -3e38f;
    for (int j = 0; j < NEXP; j++) mx = fmaxf(mx, lg[j]);
    float p[NEXP]; float sum = 0.f;
    for (int j = 0; j < NEXP; j++) { p[j] = __expf(lg[j] - mx); sum += p[j]; }
    float inv = 1.f / sum;
    int idx[TOPK]; float val[TOPK];
    for (int k = 0; k < TOPK; k++) {
      int best = 0; float bv = -1.f;
      for (int j = 0; j < NEXP; j++) if (p[j] > bv) { bv = p[j]; best = j; }
      idx[k] = best; val[k] = bv * inv; p[best] = -2.f;
    }
    float wsn = val[0] + val[1] + val[2] + val[3] + 1e-6f;
    for (int k = 0; k < TOPK; k++) { topi[t*TOPK + k] = idx[k]; topw[t*TOPK + k] = val[k] / wsn; }
  }
}

// ---------------- K2: rank scan ----------------
__global__ __launch_bounds__(256) void k_scan(const int* __restrict__ topi, int* __restrict__ pos_arr,
                                              int* __restrict__ cnt_raw) {
  int p = blockIdx.x;
  int e = p >> 2, kk = p & 3;
  __shared__ int wtot[4];
  int lane = threadIdx.x & 63, wid = threadIdx.x >> 6;
  int base = 0;
  for (int t0 = 0; t0 < T_TOK; t0 += 256) {
    int t = t0 + threadIdx.x;
    bool flag = (topi[t*TOPK + kk] == e);
    unsigned long long m = __ballot(flag);
    int excl = __popcll(m & ((1ull << lane) - 1ull));
    if (lane == 0) wtot[wid] = __popcll(m);
    __syncthreads();
    int wexcl = 0, tot = 0;
#pragma unroll
    for (int w2 = 0; w2 < 4; w2++) { int v = wtot[w2]; if (w2 < wid) wexcl += v; tot += v; }
    if (flag) pos_arr[t*TOPK + kk] = base + wexcl + excl;
    base += tot;
    __syncthreads();
  }
  if (threadIdx.x == 0) cnt_raw[p] = base;
}

// ---------------- K3: offsets ----------------
__global__ void k_offsets(const int* __restrict__ cnt_raw, int* __restrict__ cnt,
                          int* __restrict__ row_base, int* __restrict__ meta) {
  if (threadIdx.x == 0 && blockIdx.x == 0) {
    int acc = 0;
    for (int p = 0; p < NEXP*TOPK; p++) {
      int c = cnt_raw[p]; if (c > CAP) c = CAP;
      cnt[p] = c; row_base[p] = acc; acc += c;
    }
    meta[0] = acc;
  }
}

// ---------------- K4: gather -> hi/lo planes ----------------
__global__ __launch_bounds__(256) void k_gather(const float* __restrict__ x, const int* __restrict__ topi,
                                                const int* __restrict__ pos_arr, const int* __restrict__ row_base,
                                                int* __restrict__ row_of, ushort* __restrict__ xhi, ushort* __restrict__ xlo) {
  int b = blockIdx.x;
  int t = b >> 2, kk = b & 3;
  int e = topi[b];
  int pos = pos_arr[b];
  int row = (pos < CAP) ? (row_base[e*TOPK + kk] + pos) : -1;
  if (threadIdx.x == 0) row_of[b] = row;
  if (row >= 0) {
    float4 v = ((const float4*)x)[(size_t)t * 256 + threadIdx.x];
    ushort4 h, l;
    split2(v.x, h.x, l.x); split2(v.y, h.y, l.y);
    split2(v.z, h.z, l.z); split2(v.w, h.w, l.w);
    ((ushort4*)xhi)[(size_t)row * 256 + threadIdx.x] = h;
    ((ushort4*)xlo)[(size_t)row * 256 + threadIdx.x] = l;
  }
}

// ---------------- split-bf16 MFMA segment GEMM, 256x128 tile (256 rows halve W re-reads) ----------------
// C[r, colG] = A[r,:1024] @ W_e[colG,:1024]^T + bias
// 4 waves; wave wv owns rows [wv*64, wv*64+64) x all 128 cols: acc[4 m][8 n].
// A: LDS [256 rows][4 slots16], XOR-4 swizzled (phys p holds logical p^((row>>1)&3)).
// W: LDS [128 cols][8 slots16] f32, XOR-8 swizzled; CVTPK to bf16 hi/lo at read.
// Linear experts (e%4==0): full 3-product split-bf16; standard: hi*hi only.
template<int OMODE>
__global__ __launch_bounds__(256) void k_mfma_gemm(
    const ushort* __restrict__ Ahi, const ushort* __restrict__ Alo,
    const float* __restrict__ W, const float* __restrict__ Bias, int Ntot, int n0c,
    float* __restrict__ Cf, ushort* __restrict__ Chi, ushort* __restrict__ Clo, int ldc,
    const int* __restrict__ row_base, const int* __restrict__ cnt, const int* __restrict__ meta) {
  int e = blockIdx.z;
  bool full = (e & 3) == 0;
  int rs = row_base[e*4];
  int re = row_base[e*4 + 3] + cnt[e*4 + 3];
  int m0 = rs + blockIdx.y * 256;
  if (m0 >= re) return;
  int nb = blockIdx.x * 128;
  int tot = meta[0];
  __shared__ ushort ldsA[2][256*32];   // [hi/lo] 16 KB each, XOR-4 swizzled slots
  __shared__ float  ldsW[128*32];      // 16 KB f32, XOR-8 swizzled slots
  int tid = threadIdx.x;
  int lane = tid & 63, wv = tid >> 6;
  int lr = lane & 15, lk = lane >> 4;
  f32x4 acc[4][8] = {};

  // A staging: 1024 units of 16B; unit u = tid + 256q -> row = u>>2 = (tid>>2)+64q,
  // chunk_log = (u&3)^((u>>3)&3) = (tid&3)^((tid>>3)&3)  (same for all q)
  int rowA = tid >> 2;
  int kc = (((tid & 3) ^ ((tid >> 3) & 3))) << 3;
  size_t a_off[4];
#pragma unroll
  for (int q = 0; q < 4; q++)
    a_off[q] = (size_t)min(m0 + rowA + 64*q, tot - 1) * 1024 + kc;

  const float* wsrc[4];
#pragma unroll
  for (int q = 0; q < 4; q++) {
    int i = tid + 256*q;
    int rr = i >> 3, c = (i & 7) ^ (rr & 7);
    wsrc[q] = W + ((size_t)e * Ntot + n0c + nb + rr) * 1024 + c * 4;
  }

  for (int kb = 0; kb < 1024; kb += 32) {
#pragma unroll
    for (int q = 0; q < 4; q++)
      gload16(Ahi + a_off[q] + kb, &ldsA[0][(uint)(tid + 256*q) * 8]);
    if (full) {
#pragma unroll
      for (int q = 0; q < 4; q++)
        gload16(Alo + a_off[q] + kb, &ldsA[1][(uint)(tid + 256*q) * 8]);
    }
#pragma unroll
    for (int q = 0; q < 4; q++)
      gload16(wsrc[q] + kb, &ldsW[(uint)(tid + 256*q) * 4]);
    __syncthreads();

    short8 ah[4], al[4];
#pragma unroll
    for (int m = 0; m < 4; m++) {
      int rA = wv*64 + m*16 + lr;
      int sA = (lk ^ ((rA >> 1) & 3)) << 3;
      ah[m] = *(const short8*)&ldsA[0][rA*32 + sA];
    }
    if (full) {
#pragma unroll
      for (int m = 0; m < 4; m++) {
        int rA = wv*64 + m*16 + lr;
        int sA = (lk ^ ((rA >> 1) & 3)) << 3;
        al[m] = *(const short8*)&ldsA[1][rA*32 + sA];
      }
#pragma unroll
      for (int n = 0; n < 8; n++) {
        int rB = n*16 + lr;
        int x7 = rB & 7;
        float4 w0 = *(const float4*)&ldsW[rB*32 + (((lk*2)     ^ x7) << 2)];
        float4 w1 = *(const float4*)&ldsW[rB*32 + (((lk*2 + 1) ^ x7) << 2)];
        uint hp0, hp1, hp2, hp3, lp0, lp1, lp2, lp3;
        CVTPK(w0.x, w0.y, hp0, lp0);
        CVTPK(w0.z, w0.w, hp1, lp1);
        CVTPK(w1.x, w1.y, hp2, lp2);
        CVTPK(w1.z, w1.w, hp3, lp3);
        uint4 hv = make_uint4(hp0, hp1, hp2, hp3);
        uint4 lv = make_uint4(lp0, lp1, lp2, lp3);
        short8 bh = __builtin_bit_cast(short8, hv);
        short8 bl = __builtin_bit_cast(short8, lv);
#pragma unroll
        for (int m = 0; m < 4; m++) {
          acc[m][n] = __builtin_amdgcn_mfma_f32_16x16x32_bf16(ah[m], bh, acc[m][n], 0, 0, 0);
          acc[m][n] = __builtin_amdgcn_mfma_f32_16x16x32_bf16(ah[m], bl, acc[m][n], 0, 0, 0);
          acc[m][n] = __builtin_amdgcn_mfma_f32_16x16x32_bf16(al[m], bh, acc[m][n], 0, 0, 0);
        }
      }
    } else {
#pragma unroll
      for (int n = 0; n < 8; n++) {
        int rB = n*16 + lr;
        int x7 = rB & 7;
        float4 w0 = *(const float4*)&ldsW[rB*32 + (((lk*2)     ^ x7) << 2)];
        float4 w1 = *(const float4*)&ldsW[rB*32 + (((lk*2 + 1) ^ x7) << 2)];
        uint hp0, hp1, hp2, hp3;
        CVTPK_HI(w0.x, w0.y, hp0);
        CVTPK_HI(w0.z, w0.w, hp1);
        CVTPK_HI(w1.x, w1.y, hp2);
        CVTPK_HI(w1.z, w1.w, hp3);
        uint4 hv = make_uint4(hp0, hp1, hp2, hp3);
        short8 bh = __builtin_bit_cast(short8, hv);
#pragma unroll
        for (int m = 0; m < 4; m++)
          acc[m][n] = __builtin_amdgcn_mfma_f32_16x16x32_bf16(ah[m], bh, acc[m][n], 0, 0, 0);
      }
    }
    __syncthreads();
  }
#pragma unroll
  for (int n = 0; n < 8; n++) {
    int colG = n0c + nb + n*16 + lr;
    float bi = Bias[(size_t)e * Ntot + colG];
#pragma unroll
    for (int m = 0; m < 4; m++) {
      int rb = m0 + wv*64 + m*16 + lk*4;
#pragma unroll
      for (int g = 0; g < 4; g++) {
        int r = rb + g;
        if (r < re) {
          float v = acc[m][n][g] + bi;
          if constexpr (OMODE == 0) {
            Cf[(size_t)r * ldc + colG] = v;
          } else if constexpr (OMODE == 1) {
            Chi[(size_t)r * ldc + colG] = f2bf(v);
          } else {
            if (full) {
              ushort h, l; split2(v, h, l);
              Chi[(size_t)r * ldc + colG] = h;
              Clo[(size_t)r * ldc + colG] = l;
            } else {
              Chi[(size_t)r * ldc + colG] = f2bf(v);
            }
          }
        }
      }
    }
  }
}

// ---------------- exact f32 denominator bypass for linear experts ----------------
__global__ __launch_bounds__(256) void k_xsum(const ushort* __restrict__ xhi, const ushort* __restrict__ xlo,
                                              const int* __restrict__ row_base, const int* __restrict__ cnt,
                                              float* __restrict__ xsum) {
  int li = blockIdx.x;
  int z = (li >> 2) * 16 + (li & 3);
  int n = cnt[z], base = row_base[z];
  int t = threadIdx.x;
  float a0 = 0.f, a1 = 0.f, a2 = 0.f, a3 = 0.f;
  for (int r = 0; r < n; r++) {
    ushort4 h = ((const ushort4*)(xhi + (size_t)(base + r) * 1024))[t];
    ushort4 l = ((const ushort4*)(xlo + (size_t)(base + r) * 1024))[t];
    a0 += bf2f(h.x) + bf2f(l.x); a1 += bf2f(h.y) + bf2f(l.y);
    a2 += bf2f(h.z) + bf2f(l.z); a3 += bf2f(h.w) + bf2f(l.w);
  }
  float4 o = make_float4(a0, a1, a2, a3);
  ((float4*)(xsum + (size_t)li * 1024))[t] = o;
}

// ksum[li][d] = sum_h Wk[e][d][h]*xsum[li][h] + n*bk[e][d]
__global__ __launch_bounds__(256) void k_kmv1b(const float* __restrict__ qkvw, const float* __restrict__ qkvb,
                                               const float* __restrict__ xsum, const int* __restrict__ cnt,
                                               float* __restrict__ ksum) {
  int ei = blockIdx.x;
  int e = ei * 4;
  int dblk = blockIdx.y;
  __shared__ float xs[4][1024];
  for (int i = threadIdx.x; i < 4096; i += 256) {
    int sl = i >> 10, h = i & 1023;
    xs[sl][h] = xsum[(size_t)(ei*4 + sl) * 1024 + h];
  }
  __syncthreads();
  int d_loc = threadIdx.x >> 3, hc = threadIdx.x & 7;
  int d = dblk * 32 + d_loc;
  const float* wrow = qkvw + ((size_t)e * 3072 + 1024 + d) * 1024;
  float a0 = 0.f, a1 = 0.f, a2 = 0.f, a3 = 0.f;
  for (int j = 0; j < 8; j++) {
    int h0 = j * 128 + hc * 16;
#pragma unroll
    for (int q = 0; q < 4; q++) {
      float4 wv = *(const float4*)(wrow + h0 + q*4);
#pragma unroll
      for (int b = 0; b < 4; b++) {
        float wf = (b == 0) ? wv.x : (b == 1) ? wv.y : (b == 2) ? wv.z : wv.w;
        int h = h0 + q*4 + b;
        a0 += wf * xs[0][h]; a1 += wf * xs[1][h];
        a2 += wf * xs[2][h]; a3 += wf * xs[3][h];
      }
    }
  }
  for (int m = 1; m < 8; m <<= 1) {
    a0 += __shfl_xor(a0, m); a1 += __shfl_xor(a1, m);
    a2 += __shfl_xor(a2, m); a3 += __shfl_xor(a3, m);
  }
  if (hc == 0) {
    float bk = qkvb[(size_t)e * 3072 + 1024 + d];
#pragma unroll
    for (int sl = 0; sl < 4; sl++) {
      float n = (float)cnt[ei * 16 + sl];
      float v = (sl == 0) ? a0 : (sl == 1) ? a1 : (sl == 2) ? a2 : a3;
      ksum[(size_t)(ei*4 + sl) * 1024 + d] = v + n * bk;
    }
  }
}

__global__ __launch_bounds__(256) void k_kmv2b(const float* __restrict__ qkvw, const float* __restrict__ ksum,
                                               float* __restrict__ upart) {
  int ei = blockIdx.x;
  int hb = blockIdx.y;
  int dc = blockIdx.z;
  int e = ei * 4;
  __shared__ float ks[4][128];
  for (int i = threadIdx.x; i < 512; i += 256) {
    int sl = i >> 7, d = i & 127;
    ks[sl][d] = ksum[(size_t)(ei*4 + sl) * 1024 + dc*128 + d];
  }
  __syncthreads();
  int h = hb * 256 + threadIdx.x;
  float a0 = 0.f, a1 = 0.f, a2 = 0.f, a3 = 0.f;
  const float* wq = qkvw + (size_t)e * 3072 * 1024 + (size_t)(dc * 128) * 1024 + h;
  for (int d = 0; d < 128; d++) {
    float wf = wq[(size_t)d * 1024];
    a0 += wf * ks[0][d]; a1 += wf * ks[1][d];
    a2 += wf * ks[2][d]; a3 += wf * ks[3][d];
  }
  size_t ob = (size_t)(ei*8 + dc) * 4096;
  upart[ob + 0*1024 + h] = a0;
  upart[ob + 1*1024 + h] = a1;
  upart[ob + 2*1024 + h] = a2;
  upart[ob + 3*1024 + h] = a3;
}

__global__ __launch_bounds__(256) void k_kmv2r(const float* __restrict__ upart, float* __restrict__ uvec) {
  int li = blockIdx.x;
  int ei = li >> 2, sl = li & 3;
  int h = blockIdx.y * 256 + threadIdx.x;
  float a = 0.f;
  for (int dc = 0; dc < 8; dc++)
    a += upart[(size_t)(ei*8 + dc) * 4096 + (size_t)sl * 1024 + h];
  uvec[(size_t)li * 1024 + h] = a;
}

__global__ __launch_bounds__(256) void k_cdot(const float* __restrict__ qkvb, const float* __restrict__ ksum,
                                              float* __restrict__ cvec) {
  int li = blockIdx.x;
  int e = (li >> 2) * 4;
  const float* bq = qkvb + (size_t)e * 3072;
  const float* ks = ksum + (size_t)li * 1024;
  float acc = 0.f;
  for (int d = threadIdx.x; d < 1024; d += 256) acc += bq[d] * ks[d];
  __shared__ float red[256];
  red[threadIdx.x] = acc;
  __syncthreads();
  for (int s = 128; s > 0; s >>= 1) {
    if (threadIdx.x < s) red[threadIdx.x] += red[threadIdx.x + s];
    __syncthreads();
  }
  if (threadIdx.x == 0) cvec[li] = red[0];
}

__global__ __launch_bounds__(256) void k_denom(const ushort* __restrict__ xhi, const ushort* __restrict__ xlo,
                                               const float* __restrict__ uvec, const float* __restrict__ cvec,
                                               const int* __restrict__ row_base, const int* __restrict__ cnt,
                                               float* __restrict__ denomArr) {
  int li = blockIdx.y;
  int z = (li >> 2) * 16 + (li & 3);
  int n = cnt[z], base = row_base[z];
  int g = threadIdx.x >> 5, lane = threadIdx.x & 31;
  int r = blockIdx.x * 8 + g;
  if (r >= n) return;
  const ushort* xh = xhi + (size_t)(base + r) * 1024;
  const ushort* xl = xlo + (size_t)(base + r) * 1024;
  const float* u = uvec + (size_t)li * 1024;
  float dn = 0.f;
  for (int j = 0; j < 32; j++) {
    int h = lane + j * 32;
    dn += (bf2f(xh[h]) + bf2f(xl[h])) * u[h];
  }
  dn += __shfl_xor(dn, 1); dn += __shfl_xor(dn, 2); dn += __shfl_xor(dn, 4);
  dn += __shfl_xor(dn, 8); dn += __shfl_xor(dn, 16);
  if (lane == 0) denomArr[base + r] = dn + cvec[li];
}

// ---------------- K6a: MFMA flash attention (standard experts) ----------------
__global__ __launch_bounds__(256) void k_attn_std(const ushort* __restrict__ qkv,
                                                  ushort* __restrict__ ahi, ushort* __restrict__ alo,
                                                  const int* __restrict__ row_base, const int* __restrict__ cnt,
                                                  const int* __restrict__ meta) {
  int z = blockIdx.z;
  int e = z >> 2;
  if ((e & 3) == 0) return;
  int n = cnt[z];
  int q0 = blockIdx.x * 64;
  if (q0 >= n) return;
  int h = blockIdx.y;
  int base = row_base[z];
  int tot = meta[0];

  __shared__ ushort Kb[32*264];
  __shared__ ushort Vt[256*40];
  __shared__ ushort Pb[4*16*40];

  int tid = threadIdx.x;
  int lane = tid & 63, w = tid >> 6;
  int lr = lane & 15, lk = lane >> 4;

  int qrow = base + q0 + w*16 + lr;
  const ushort* qptr = qkv + (size_t)min(qrow, tot - 1) * 3072 + h*256 + lk*8;
  short8 qf[8];
#pragma unroll
  for (int f = 0; f < 8; f++) qf[f] = *(const short8*)(qptr + f*32);

  f32x4 Oacc[16];
#pragma unroll
  for (int db = 0; db < 16; db++) Oacc[db] = (f32x4){0.f, 0.f, 0.f, 0.f};
  float m_run[4], l_run[4];
#pragma unroll
  for (int g = 0; g < 4; g++) { m_run[g] = -3e38f; l_run[g] = 0.f; }

  int ntile = (n + 31) >> 5;
  for (int t = 0; t < ntile; t++) {
    __syncthreads();
    for (int s = tid; s < 1024; s += 256) {
      int key = s >> 5, ch = s & 31;
      int krow = t*32 + key;
      short8 v = {0,0,0,0,0,0,0,0};
      if (krow < n) v = *(const short8*)(qkv + (size_t)(base + krow)*3072 + 1024 + h*256 + ch*8);
      *(short8*)(Kb + key*264 + ch*8) = v;
    }
    {
      int k2 = tid >> 3, dg = tid & 7;
      bool kval = (t*32 + k2) < n;
      const ushort* vsrc = qkv + (size_t)(base + min(t*32 + k2, n - 1))*3072 + 2048 + h*256 + dg*8;
#pragma unroll
      for (int tt = 0; tt < 4; tt++) {
        int dd = dg*8 + tt*64;
        short8 v = {0,0,0,0,0,0,0,0};
        if (kval) v = *(const short8*)(vsrc + tt*64);
#pragma unroll
        for (int j = 0; j < 8; j++) Vt[(dd + j)*40 + k2] = ((ushort*)&v)[j];
      }
    }
    __syncthreads();
    f32x4 S0 = (f32x4){0.f,0.f,0.f,0.f}, S1 = (f32x4){0.f,0.f,0.f,0.f};
#pragma unroll
    for (int db = 0; db < 8; db++) {
      short8 b0 = *(const short8*)(Kb + lr*264 + db*32 + lk*8);
      short8 b1 = *(const short8*)(Kb + (16 + lr)*264 + db*32 + lk*8);
      S0 = __builtin_amdgcn_mfma_f32_16x16x32_bf16(qf[db], b0, S0, 0, 0, 0);
      S1 = __builtin_amdgcn_mfma_f32_16x16x32_bf16(qf[db], b1, S1, 0, 0, 0);
    }
    bool v0 = (t*32 + lr) < n, v1 = (t*32 + 16 + lr) < n;
    float p0v[4], p1v[4], scv[4];
#pragma unroll
    for (int g = 0; g < 4; g++) {
      float s0 = v0 ? S0[g] * 0.0625f : -1e9f;
      float s1 = v1 ? S1[g] * 0.0625f : -1e9f;
      float mx = fmaxf(s0, s1);
      mx = fmaxf(mx, __shfl_xor(mx, 1)); mx = fmaxf(mx, __shfl_xor(mx, 2));
      mx = fmaxf(mx, __shfl_xor(mx, 4)); mx = fmaxf(mx, __shfl_xor(mx, 8));
      float nm = fmaxf(m_run[g], mx);
      float sc = __expf(m_run[g] - nm);
      m_run[g] = nm;
      float p0 = __expf(s0 - nm), p1 = __expf(s1 - nm);
      float sum = p0 + p1;
      sum += __shfl_xor(sum, 1); sum += __shfl_xor(sum, 2);
      sum += __shfl_xor(sum, 4); sum += __shfl_xor(sum, 8);
      l_run[g] = l_run[g] * sc + sum;
      p0v[g] = p0; p1v[g] = p1; scv[g] = sc;
    }
#pragma unroll
    for (int db = 0; db < 16; db++)
#pragma unroll
      for (int g = 0; g < 4; g++) Oacc[db][g] *= scv[g];
    ushort* pw = Pb + w*640;
#pragma unroll
    for (int g = 0; g < 4; g++) {
      int q = lk*4 + g;
      pw[q*40 + lr] = f2bf(p0v[g]);
      pw[q*40 + 16 + lr] = f2bf(p1v[g]);
    }
    __syncthreads();
    short8 pa = *(const short8*)(pw + lr*40 + lk*8);
#pragma unroll
    for (int db = 0; db < 16; db++) {
      short8 vb = *(const short8*)(Vt + (db*16 + lr)*40 + lk*8);
      Oacc[db] = __builtin_amdgcn_mfma_f32_16x16x32_bf16(pa, vb, Oacc[db], 0, 0, 0);
    }
  }
#pragma unroll
  for (int g = 0; g < 4; g++) {
    int qr = q0 + w*16 + lk*4 + g;
    if (qr < n) {
      float inv = 1.f / l_run[g];
      size_t ro = (size_t)(base + qr) * 1024 + h*256;
#pragma unroll
      for (int db = 0; db < 16; db++) {
        float v = Oacc[db][g] * inv;
        ushort hh, ll; split2(v, hh, ll);
        ahi[ro + db*16 + lr] = hh;
        alo[ro + db*16 + lr] = ll;
      }
    }
  }
}

// ---------------- K6b-A: linear attention S = Q.K^T (MFMA) ----------------
__global__ __launch_bounds__(256) void k_lin_qkt(const ushort* __restrict__ qkv,
                                                 ushort* __restrict__ Shi, ushort* __restrict__ Slo,
                                                 const int* __restrict__ row_base, const int* __restrict__ cnt) {
  int li = blockIdx.z;
  int z = (li >> 2) * 16 + (li & 3);
  int n = cnt[z];
  int q0 = blockIdx.y * 128, k0 = blockIdx.x * 128;
  if (q0 >= n || k0 >= n) return;
  int base = row_base[z];
  __shared__ ushort lds[2][128*32];
  int tid = threadIdx.x;
  int lane = tid & 63, w = tid >> 6;
  int wr = w >> 1, wc = w & 1;
  int lr = lane & 15, lk = lane >> 4;
  f32x4 acc[4][4] = {};
  int r0 = tid >> 2;
  int kc = (tid & 3) << 3;
  size_t a0 = (size_t)(base + min(q0 + r0, n - 1)) * 3072 + kc;
  size_t a1 = (size_t)(base + min(q0 + 64 + r0, n - 1)) * 3072 + kc;
  size_t b0 = (size_t)(base + min(k0 + r0, n - 1)) * 3072 + 1024 + kc;
  size_t b1 = (size_t)(base + min(k0 + 64 + r0, n - 1)) * 3072 + 1024 + kc;
  uint d0 = (uint)tid * 8, d1 = (uint)(256 + tid) * 8;
  for (int kb = 0; kb < 1024; kb += 32) {
    gload16(qkv + a0 + kb, &lds[0][d0]);
    gload16(qkv + a1 + kb, &lds[0][d1]);
    gload16(qkv + b0 + kb, &lds[1][d0]);
    gload16(qkv + b1 + kb, &lds[1][d1]);
    __syncthreads();
    short8 af[4], bf[4];
#pragma unroll
    for (int m = 0; m < 4; m++) af[m] = *(const short8*)&lds[0][(wr*64 + m*16 + lr)*32 + lk*8];
#pragma unroll
    for (int n2 = 0; n2 < 4; n2++) bf[n2] = *(const short8*)&lds[1][(wc*64 + n2*16 + lr)*32 + lk*8];
#pragma unroll
    for (int m = 0; m < 4; m++)
#pragma unroll
      for (int n2 = 0; n2 < 4; n2++)
        acc[m][n2] = __builtin_amdgcn_mfma_f32_16x16x32_bf16(af[m], bf[n2], acc[m][n2], 0, 0, 0);
    __syncthreads();
  }
#pragma unroll
  for (int n2 = 0; n2 < 4; n2++) {
    int col = k0 + wc*64 + n2*16 + lr;
#pragma unroll
    for (int m = 0; m < 4; m++) {
#pragma unroll
      for (int g = 0; g < 4; g++) {
        int row = q0 + wr*64 + m*16 + lk*4 + g;
        if (row < n) {
          float v = (col < n) ? acc[m][n2][g] : 0.f;
          ushort hh, ll; split2(v, hh, ll);
          size_t o = (size_t)li * (CAP*CAP) + (size_t)row * CAP + col;
          Shi[o] = hh; Slo[o] = ll;
        }
      }
    }
  }
}

// ---------------- K6b-B: linear attention O = (Shi+Slo).V * zq (MFMA) ----------------
__global__ __launch_bounds__(256) void k_lin_pv(const ushort* __restrict__ qkv,
                                                const ushort* __restrict__ Shi, const ushort* __restrict__ Slo,
                                                ushort* __restrict__ ahi, ushort* __restrict__ alo,
                                                const int* __restrict__ row_base, const int* __restrict__ cnt,
                                                const float* __restrict__ denomArr) {
  int li = blockIdx.y;
  int z = (li >> 2) * 16 + (li & 3);
  int n = cnt[z];
  int q0 = blockIdx.x * 64;
  if (q0 >= n) return;
  int base = row_base[z];
  __shared__ ushort Vt[256*40];
  int tid = threadIdx.x;
  int lane = tid & 63, w = tid >> 6;
  int lr = lane & 15, lk = lane >> 4;
  int ntile = (n + 31) >> 5;
  int k2 = tid >> 3, dg = tid & 7;
  int qrow = min(q0 + w*16 + lr, n - 1);
  const ushort* srowH = Shi + (size_t)li * (CAP*CAP) + (size_t)qrow * CAP;
  const ushort* srowL = Slo + (size_t)li * (CAP*CAP) + (size_t)qrow * CAP;
  for (int c = 0; c < 4; c++) {
    f32x4 Oacc[16];
#pragma unroll
    for (int db = 0; db < 16; db++) Oacc[db] = (f32x4){0.f, 0.f, 0.f, 0.f};
    for (int t = 0; t < ntile; t++) {
      __syncthreads();
      int krow = t*32 + k2;
      bool kval = krow < n;
      const ushort* vsrc = qkv + (size_t)(base + min(krow, n - 1))*3072 + 2048 + c*256 + dg*8;
#pragma unroll
      for (int tt = 0; tt < 4; tt++) {
        int dd = dg*8 + tt*64;
        short8 v = {0,0,0,0,0,0,0,0};
        if (kval) v = *(const short8*)(vsrc + tt*64);
#pragma unroll
        for (int j = 0; j < 8; j++) Vt[(dd + j)*40 + k2] = ((ushort*)&v)[j];
      }
      __syncthreads();
      short8 ph = *(const short8*)(srowH + t*32 + lk*8);
      short8 pl = *(const short8*)(srowL + t*32 + lk*8);
#pragma unroll
      for (int db = 0; db < 16; db++) {
        short8 vb = *(const short8*)(Vt + (db*16 + lr)*40 + lk*8);
        Oacc[db] = __builtin_amdgcn_mfma_f32_16x16x32_bf16(ph, vb, Oacc[db], 0, 0, 0);
        Oacc[db] = __builtin_amdgcn_mfma_f32_16x16x32_bf16(pl, vb, Oacc[db], 0, 0, 0);
      }
    }
#pragma unroll
    for (int g = 0; g < 4; g++) {
      int qr = q0 + w*16 + lk*4 + g;
      if (qr < n) {
        float zq = 1.f / (denomArr[base + qr] + 1e-6f);
        size_t ro = (size_t)(base + qr) * 1024 + c*256;
#pragma unroll
        for (int db = 0; db < 16; db++) {
          float v = Oacc[db][g] * zq;
          ushort hh, ll; split2(v, hh, ll);
          ahi[ro + db*16 + lr] = hh;
          alo[ro + db*16 + lr] = ll;
        }
      }
    }
  }
}

// ---------------- K8: g = u * silu(gate) ----------------
__global__ __launch_bounds__(256) void k_silu(const float* __restrict__ hgl, ushort* __restrict__ ghi,
                                              ushort* __restrict__ glo, const int* __restrict__ meta) {
  int r = blockIdx.x;
  if (r >= meta[0]) return;
  const float4* u4 = (const float4*)(hgl + (size_t)r * 2048);
  float4 u = u4[threadIdx.x];
  float4 gt = u4[256 + threadIdx.x];
  float4 o;
  o.x = u.x * (gt.x / (1.f + __expf(-gt.x)));
  o.y = u.y * (gt.y / (1.f + __expf(-gt.y)));
  o.z = u.z * (gt.z / (1.f + __expf(-gt.z)));
  o.w = u.w * (gt.w / (1.f + __expf(-gt.w)));
  ushort4 h, l;
  split2(o.x, h.x, l.x); split2(o.y, h.y, l.y);
  split2(o.z, h.z, l.z); split2(o.w, h.w, l.w);
  ((ushort4*)ghi)[(size_t)r * 256 + threadIdx.x] = h;
  ((ushort4*)glo)[(size_t)r * 256 + threadIdx.x] = l;
}

// ---------------- K11: weighted scatter ----------------
__global__ __launch_bounds__(256) void k_scatter(const float* __restrict__ o, const int* __restrict__ row_of,
                                                 const float* __restrict__ topw, float* __restrict__ out) {
  int t = blockIdx.x;
  float4 acc = make_float4(0.f, 0.f, 0.f, 0.f);
  for (int k = 0; k < TOPK; k++) {
    int row = row_of[t*TOPK + k];
    if (row >= 0) {
      float w = topw[t*TOPK + k];
      float4 v = ((const float4*)o)[(size_t)row * 256 + threadIdx.x];
      acc.x += w * v.x; acc.y += w * v.y; acc.z += w * v.z; acc.w += w * v.w;
    }
  }
  ((float4*)out)[(size_t)t * 256 + threadIdx.x] = acc;
}

extern "C" void kernel_launch(void* const* d_in, const int* in_sizes, int n_in,
                              void* d_out, int out_size, void* d_ws, size_t ws_size,
                              hipStream_t stream) {
  const float* x    = (const float*)d_in[0];
  const float* rw   = (const float*)d_in[1];
  const float* qkvw = (const float*)d_in[2];
  const float* qkvb = (const float*)d_in[3];
  const float* sww  = (const float*)d_in[4];
  const float* swb  = (const float*)d_in[5];
  const float* svw  = (const float*)d_in[6];
  const float* svb  = (const float*)d_in[7];
  const float* pjw  = (const float*)d_in[8];
  const float* pjb  = (const float*)d_in[9];
  float* out = (float*)d_out;

  char* ws = (char*)d_ws;
  const size_t MB = 1ull << 20;
  ushort* xhi  = (ushort*)(ws + 0);
  ushort* xlo  = (ushort*)(ws + 32*MB);
  ushort* qkvB = (ushort*)(ws + 64*MB);
  ushort* ahi  = (ushort*)(ws + 160*MB);
  ushort* alo  = (ushort*)(ws + 192*MB);
  ushort* Shi  = (ushort*)(ws + 224*MB);
  ushort* Slo  = (ushort*)(ws + 240*MB);
  float*  hgl  = (float*)(ws + 0);
  ushort* ghi  = ahi;
  ushort* glo  = alo;
  ushort* shi  = (ushort*)(ws + 0);
  ushort* slo  = (ushort*)(ws + 32*MB);
  float*  obuf = (float*)(ws + 64*MB);
  char* sm = ws + 288*MB;
  size_t off = 0;
  auto alloc = [&](size_t bytes) { char* p = sm + off; off += (bytes + 255) & ~(size_t)255; return p; };
  int*   topi = (int*)alloc(T_TOK*TOPK*4);
  float* topw = (float*)alloc(T_TOK*TOPK*4);
  int*   pos  = (int*)alloc(T_TOK*TOPK*4);
  int*   rof  = (int*)alloc(T_TOK*TOPK*4);
  int*   craw = (int*)alloc(NEXP*TOPK*4);
  int*   cnt  = (int*)alloc(NEXP*TOPK*4);
  int*   rbase= (int*)alloc(NEXP*TOPK*4);
  int*   meta = (int*)alloc(256);
  float* xsum = (float*)alloc(32*1024*4);
  float* ksum = (float*)alloc(32*1024*4);
  float* uvec = (float*)alloc(32*1024*4);
  float* cvec = (float*)alloc(32*4);
  float* denomArr = (float*)alloc(MAXROWS*4);
  float* upart = (float*)alloc(8*8*4*1024*4);

  k_router <<<T_TOK, 256, 0, stream>>>(x, rw, topi, topw);
  k_scan   <<<NEXP*TOPK, 256, 0, stream>>>(topi, pos, craw);
  k_offsets<<<1, 64, 0, stream>>>(craw, cnt, rbase, meta);
  k_gather <<<T_TOK*TOPK, 256, 0, stream>>>(x, topi, pos, rbase, rof, xhi, xlo);

  // exact f32 denominator bypass (linear experts)
  k_xsum  <<<32, 256, 0, stream>>>(xhi, xlo, rbase, cnt, xsum);
  k_kmv1b <<<dim3(8, 32), 256, 0, stream>>>(qkvw, qkvb, xsum, cnt, ksum);
  k_kmv2b <<<dim3(8, 4, 8), 256, 0, stream>>>(qkvw, ksum, upart);
  k_kmv2r <<<dim3(32, 4), 256, 0, stream>>>(upart, uvec);
  k_cdot  <<<32, 256, 0, stream>>>(qkvb, ksum, cvec);
  k_denom <<<dim3(64, 32), 256, 0, stream>>>(xhi, xlo, uvec, cvec, rbase, cnt, denomArr);

  // GEMMs: one dispatch per layer, full N; 256-row tiles (y=8 covers 2048 rows max)
  dim3 gqkv(3072/128, 8, NEXP);
  k_mfma_gemm<1><<<gqkv, 256, 0, stream>>>(xhi, xlo, qkvw, qkvb, 3072, 0,
                                           nullptr, qkvB, nullptr, 3072, rbase, cnt, meta);

  dim3 ga(CAP/64, NH, NEXP*TOPK);
  k_attn_std<<<ga, 256, 0, stream>>>(qkvB, ahi, alo, rbase, cnt, meta);
  dim3 gq(CAP/128, CAP/128, 32);
  k_lin_qkt<<<gq, 256, 0, stream>>>(qkvB, Shi, Slo, rbase, cnt);
  dim3 gp(CAP/64, 32);
  k_lin_pv<<<gp, 256, 0, stream>>>(qkvB, Shi, Slo, ahi, alo, rbase, cnt, denomArr);

  dim3 gsw(2048/128, 8, NEXP);
  k_mfma_gemm<0><<<gsw, 256, 0, stream>>>(ahi, alo, sww, swb, 2048, 0,
                                          hgl, nullptr, nullptr, 2048, rbase, cnt, meta);
  k_silu<<<MAXROWS, 256, 0, stream>>>(hgl, ghi, glo, meta);

  dim3 g1k(1024/128, 8, NEXP);
  k_mfma_gemm<2><<<g1k, 256, 0, stream>>>(ghi, glo, svw, svb, 1024, 0,
                                          nullptr, shi, slo, 1024, rbase, cnt, meta);
  k_mfma_gemm<0><<<g1k, 256, 0, stream>>>(shi, slo, pjw, pjb, 1024, 0,
                                          obuf, nullptr, nullptr, 1024, rbase, cnt, meta);

  k_scatter<<<T_TOK, 256, 0, stream>>>(obuf, rof, topw, out);
}

// Round 13
// 1517.192 us; speedup vs baseline: 1.5497x; 1.5497x over previous
//
#include <hip/hip_runtime.h>
#include <hip/hip_bf16.h>
#include <cstdint>

#define T_TOK 4096
#define NEXP  32
#define TOPK  4
#define CAP   512
#define H     1024
#define E     1024
#define NH    4
#define HD    256
#define MAXROWS (T_TOK*TOPK)   // 16384

typedef __attribute__((ext_vector_type(4))) float f32x4;
typedef __attribute__((ext_vector_type(8))) short short8;

__device__ __forceinline__ float bf2f(ushort u) {
  return __uint_as_float(((uint)u) << 16);
}
__device__ __forceinline__ ushort f2bf(float f) {
  uint u = __float_as_uint(f);
  uint r = (u + 0x7fffu + ((u >> 16) & 1u)) >> 16;
  return (ushort)r;
}
__device__ __forceinline__ void split2(float v, ushort& h, ushort& l) {
  h = f2bf(v);
  l = f2bf(v - bf2f(h));
}
__device__ __forceinline__ void gload16(const void* g, void* l) {
  __builtin_amdgcn_global_load_lds((const __attribute__((address_space(1))) void*)g,
                                   (__attribute__((address_space(3))) void*)l, 16, 0, 0);
}

// packed f32 pair -> (hi bf16x2, lo bf16x2); RNE, bit-identical to split2
#define CVTPK(F0, F1, HP, LP) do { \
  asm("v_cvt_pk_bf16_f32 %0, %1, %2" : "=v"(HP) : "v"(F0), "v"(F1)); \
  float _h0 = __uint_as_float((HP) << 16); \
  float _h1 = __uint_as_float((HP) & 0xffff0000u); \
  float _l0 = (F0) - _h0, _l1 = (F1) - _h1; \
  asm("v_cvt_pk_bf16_f32 %0, %1, %2" : "=v"(LP) : "v"(_l0), "v"(_l1)); \
} while (0)

// ---------------- K1: router ----------------
__global__ __launch_bounds__(256) void k_router(const float* __restrict__ x, const float* __restrict__ rw,
                                                int* __restrict__ topi, float* __restrict__ topw) {
  int t = blockIdx.x;
  __shared__ float4 xs[256];
  __shared__ float lg[NEXP];
  const float4* xr = (const float4*)(x + (size_t)t * H);
  xs[threadIdx.x] = xr[threadIdx.x];
  __syncthreads();
  int g = threadIdx.x >> 3, s = threadIdx.x & 7;
  const float4* wr = (const float4*)(rw + (size_t)g * H);
  float acc = 0.f;
  for (int j = s; j < 256; j += 8) {
    float4 a = xs[j], b = wr[j];
    acc += a.x * b.x + a.y * b.y + a.z * b.z + a.w * b.w;
  }
  acc += __shfl_xor(acc, 1);
  acc += __shfl_xor(acc, 2);
  acc += __shfl_xor(acc, 4);
  if (s == 0) lg[g] = acc;
  __syncthreads();
  if (threadIdx.x == 0) {
    float mx = -3e38f;
    for (int j = 0; j < NEXP; j++) mx = fmaxf(mx, lg[j]);
    float p[NEXP]; float sum = 0.f;
    for (int j = 0; j < NEXP; j++) { p[j] = __expf(lg[j] - mx); sum += p[j]; }
    float inv = 1.f / sum;
    int idx[TOPK]; float val[TOPK];
    for (int k = 0; k < TOPK; k++) {
      int best = 0; float bv = -1.f;
      for (int j = 0; j < NEXP; j++) if (p[j] > bv) { bv = p[j]; best = j; }
      idx[k] = best; val[k] = bv * inv; p[best] = -2.f;
    }
    float wsn = val[0] + val[1] + val[2] + val[3] + 1e-6f;
    for (int k = 0; k < TOPK; k++) { topi[t*TOPK + k] = idx[k]; topw[t*TOPK + k] = val[k] / wsn; }
  }
}

// ---------------- K2: rank scan ----------------
__global__ __launch_bounds__(256) void k_scan(const int* __restrict__ topi, int* __restrict__ pos_arr,
                                              int* __restrict__ cnt_raw) {
  int p = blockIdx.x;
  int e = p >> 2, kk = p & 3;
  __shared__ int wtot[4];
  int lane = threadIdx.x & 63, wid = threadIdx.x >> 6;
  int base = 0;
  for (int t0 = 0; t0 < T_TOK; t0 += 256) {
    int t = t0 + threadIdx.x;
    bool flag = (topi[t*TOPK + kk] == e);
    unsigned long long m = __ballot(flag);
    int excl = __popcll(m & ((1ull << lane) - 1ull));
    if (lane == 0) wtot[wid] = __popcll(m);
    __syncthreads();
    int wexcl = 0, tot = 0;
#pragma unroll
    for (int w2 = 0; w2 < 4; w2++) { int v = wtot[w2]; if (w2 < wid) wexcl += v; tot += v; }
    if (flag) pos_arr[t*TOPK + kk] = base + wexcl + excl;
    base += tot;
    __syncthreads();
  }
  if (threadIdx.x == 0) cnt_raw[p] = base;
}

// ---------------- K3: offsets ----------------
__global__ void k_offsets(const int* __restrict__ cnt_raw, int* __restrict__ cnt,
                          int* __restrict__ row_base, int* __restrict__ meta) {
  if (threadIdx.x == 0 && blockIdx.x == 0) {
    int acc = 0;
    for (int p = 0; p < NEXP*TOPK; p++) {
      int c = cnt_raw[p]; if (c > CAP) c = CAP;
      cnt[p] = c; row_base[p] = acc; acc += c;
    }
    meta[0] = acc;
  }
}

// ---------------- K4: gather -> hi/lo planes ----------------
__global__ __launch_bounds__(256) void k_gather(const float* __restrict__ x, const int* __restrict__ topi,
                                                const int* __restrict__ pos_arr, const int* __restrict__ row_base,
                                                int* __restrict__ row_of, ushort* __restrict__ xhi, ushort* __restrict__ xlo) {
  int b = blockIdx.x;
  int t = b >> 2, kk = b & 3;
  int e = topi[b];
  int pos = pos_arr[b];
  int row = (pos < CAP) ? (row_base[e*TOPK + kk] + pos) : -1;
  if (threadIdx.x == 0) row_of[b] = row;
  if (row >= 0) {
    float4 v = ((const float4*)x)[(size_t)t * 256 + threadIdx.x];
    ushort4 h, l;
    split2(v.x, h.x, l.x); split2(v.y, h.y, l.y);
    split2(v.z, h.z, l.z); split2(v.w, h.w, l.w);
    ((ushort4*)xhi)[(size_t)row * 256 + threadIdx.x] = h;
    ((ushort4*)xlo)[(size_t)row * 256 + threadIdx.x] = l;
  }
}

// ---------------- split-bf16 MFMA segment GEMM (128x128 tile, W read directly as f32) ----------------
// C[r, colG] = A[r,:1024] @ W_e[colG,:1024]^T + bias (R8-proven structure).
// OMODE: 0 = f32 out, 1 = bf16 out, 2 = hi/lo plane out,
//        3 = fused SwiGLU: block covers 64 g-cols; stages 64 u-rows + 64 gate-rows of W;
//            epilogue exchanges gate accs via LDS and writes g = u*silu(gate) hi/lo planes.
//            NOTE: OMODE3 output buffers must NOT alias the A input (cross-block race).
template<int OMODE>
__global__ __launch_bounds__(256) void k_mfma_gemm(
    const ushort* __restrict__ Ahi, const ushort* __restrict__ Alo,
    const float* __restrict__ W, const float* __restrict__ Bias, int Ntot, int n0c,
    float* __restrict__ Cf, ushort* __restrict__ Chi, ushort* __restrict__ Clo, int ldc,
    const int* __restrict__ row_base, const int* __restrict__ cnt, const int* __restrict__ meta) {
  int e = blockIdx.z;
  int rs = row_base[e*4];
  int re = row_base[e*4 + 3] + cnt[e*4 + 3];
  int m0 = rs + blockIdx.y * 128;
  if (m0 >= re) return;
  int nb = (OMODE == 3) ? blockIdx.x * 64 : blockIdx.x * 128;  // OMODE3: g-col base
  int tot = meta[0];
  __shared__ __align__(16) char smem[32768];
  ushort* ldsA0 = (ushort*)smem;             // 8 KB: A hi, XOR-4 swizzled slots
  ushort* ldsA1 = (ushort*)(smem + 8192);    // 8 KB: A lo
  float*  ldsW  = (float*)(smem + 16384);    // 16 KB: W f32, XOR-8 swizzled slots
  int tid = threadIdx.x;
  int lane = tid & 63, w = tid >> 6;
  int wr = w >> 1, wc = w & 1;
  int lr = lane & 15, lk = lane >> 4;
  f32x4 acc[4][4] = {};

  int r0 = tid >> 2;
  int gA = (tid >> 3) & 3;
  int kc = (((tid & 3) ^ gA)) << 3;
  size_t a_off0 = (size_t)min(m0 + r0, tot - 1) * 1024 + kc;
  size_t a_off1 = (size_t)min(m0 + 64 + r0, tot - 1) * 1024 + kc;
  uint d0 = (uint)tid * 8, d1 = (uint)(256 + tid) * 8;

  const float* wsrc0; const float* wsrc1; const float* wsrc2; const float* wsrc3;
  {
    auto wrow = [&](int rr) -> int {
      if (OMODE == 3) return (rr < 64) ? (nb + rr) : (1024 + nb + (rr - 64));
      return n0c + nb + rr;
    };
    int i0 = tid;           int rr0 = i0 >> 3, c0 = (i0 & 7) ^ (rr0 & 7);
    int i1 = tid + 256;     int rr1 = i1 >> 3, c1 = (i1 & 7) ^ (rr1 & 7);
    int i2 = tid + 512;     int rr2 = i2 >> 3, c2 = (i2 & 7) ^ (rr2 & 7);
    int i3 = tid + 768;     int rr3 = i3 >> 3, c3 = (i3 & 7) ^ (rr3 & 7);
    wsrc0 = W + ((size_t)e * Ntot + wrow(rr0)) * 1024 + c0 * 4;
    wsrc1 = W + ((size_t)e * Ntot + wrow(rr1)) * 1024 + c1 * 4;
    wsrc2 = W + ((size_t)e * Ntot + wrow(rr2)) * 1024 + c2 * 4;
    wsrc3 = W + ((size_t)e * Ntot + wrow(rr3)) * 1024 + c3 * 4;
  }

  for (int kb = 0; kb < 1024; kb += 32) {
    gload16(Ahi + a_off0 + kb, &ldsA0[d0]);
    gload16(Ahi + a_off1 + kb, &ldsA0[d1]);
    gload16(Alo + a_off0 + kb, &ldsA1[d0]);
    gload16(Alo + a_off1 + kb, &ldsA1[d1]);
    gload16(wsrc0 + kb, &ldsW[(uint)tid * 4]);
    gload16(wsrc1 + kb, &ldsW[(uint)(tid + 256) * 4]);
    gload16(wsrc2 + kb, &ldsW[(uint)(tid + 512) * 4]);
    gload16(wsrc3 + kb, &ldsW[(uint)(tid + 768) * 4]);
    __syncthreads();
    short8 ah[4], al[4], bh[4], bl[4];
#pragma unroll
    for (int m = 0; m < 4; m++) {
      int rA = wr*64 + m*16 + lr;
      int sA = (lk ^ ((rA >> 1) & 3)) << 3;
      ah[m] = *(const short8*)&ldsA0[rA*32 + sA];
      al[m] = *(const short8*)&ldsA1[rA*32 + sA];
    }
#pragma unroll
    for (int n = 0; n < 4; n++) {
      int rB = wc*64 + n*16 + lr;
      int x7 = rB & 7;
      float4 w0 = *(const float4*)&ldsW[rB*32 + (((lk*2)     ^ x7) << 2)];
      float4 w1 = *(const float4*)&ldsW[rB*32 + (((lk*2 + 1) ^ x7) << 2)];
      uint hp0, hp1, hp2, hp3, lp0, lp1, lp2, lp3;
      CVTPK(w0.x, w0.y, hp0, lp0);
      CVTPK(w0.z, w0.w, hp1, lp1);
      CVTPK(w1.x, w1.y, hp2, lp2);
      CVTPK(w1.z, w1.w, hp3, lp3);
      uint4 hv = make_uint4(hp0, hp1, hp2, hp3);
      uint4 lv = make_uint4(lp0, lp1, lp2, lp3);
      bh[n] = __builtin_bit_cast(short8, hv);
      bl[n] = __builtin_bit_cast(short8, lv);
    }
#pragma unroll
    for (int m = 0; m < 4; m++)
#pragma unroll
      for (int n = 0; n < 4; n++) {
        acc[m][n] = __builtin_amdgcn_mfma_f32_16x16x32_bf16(ah[m], bh[n], acc[m][n], 0, 0, 0);
        acc[m][n] = __builtin_amdgcn_mfma_f32_16x16x32_bf16(ah[m], bl[n], acc[m][n], 0, 0, 0);
        acc[m][n] = __builtin_amdgcn_mfma_f32_16x16x32_bf16(al[m], bh[n], acc[m][n], 0, 0, 0);
      }
    __syncthreads();
  }

  if constexpr (OMODE == 3) {
    // gate waves (wc==1) publish acc+bias_gate via LDS; u waves apply silu and store planes
    float* gbuf = (float*)smem;   // 128 rows x 64 cols f32 = 32 KB (full smem alias)
    if (wc == 1) {
#pragma unroll
      for (int n = 0; n < 4; n++) {
        int colL = n*16 + lr;
        float bg = Bias[(size_t)e * Ntot + 1024 + nb + colL];
#pragma unroll
        for (int m = 0; m < 4; m++) {
#pragma unroll
          for (int g = 0; g < 4; g++) {
            int rowL = wr*64 + m*16 + lk*4 + g;
            gbuf[rowL*64 + colL] = acc[m][n][g] + bg;
          }
        }
      }
    }
    __syncthreads();
    if (wc == 0) {
#pragma unroll
      for (int n = 0; n < 4; n++) {
        int colL = n*16 + lr;
        int colG = nb + colL;
        float bu = Bias[(size_t)e * Ntot + colG];
#pragma unroll
        for (int m = 0; m < 4; m++) {
          int rb = m0 + wr*64 + m*16 + lk*4;
#pragma unroll
          for (int g = 0; g < 4; g++) {
            int r = rb + g;
            if (r < re) {
              int rowL = wr*64 + m*16 + lk*4 + g;
              float gate = gbuf[rowL*64 + colL];
              float u = acc[m][n][g] + bu;
              float gv = u * (gate / (1.f + __expf(-gate)));
              ushort hh, ll; split2(gv, hh, ll);
              Chi[(size_t)r * ldc + colG] = hh;
              Clo[(size_t)r * ldc + colG] = ll;
            }
          }
        }
      }
    }
    return;
  }

#pragma unroll
  for (int n = 0; n < 4; n++) {
    int colG = n0c + nb + wc*64 + n*16 + lr;
    float bi = Bias[(size_t)e * Ntot + colG];
#pragma unroll
    for (int m = 0; m < 4; m++) {
      int rb = m0 + wr*64 + m*16 + lk*4;
#pragma unroll
      for (int g = 0; g < 4; g++) {
        int r = rb + g;
        if (r < re) {
          float v = acc[m][n][g] + bi;
          if constexpr (OMODE == 0) {
            Cf[(size_t)r * ldc + colG] = v;
          } else if constexpr (OMODE == 1) {
            Chi[(size_t)r * ldc + colG] = f2bf(v);
          } else {
            ushort h, l; split2(v, h, l);
            Chi[(size_t)r * ldc + colG] = h;
            Clo[(size_t)r * ldc + colG] = l;
          }
        }
      }
    }
  }
}

// ---------------- exact f32 denominator bypass for linear experts ----------------
__global__ __launch_bounds__(256) void k_xsum(const ushort* __restrict__ xhi, const ushort* __restrict__ xlo,
                                              const int* __restrict__ row_base, const int* __restrict__ cnt,
                                              float* __restrict__ xsum) {
  int li = blockIdx.x;
  int z = (li >> 2) * 16 + (li & 3);
  int n = cnt[z], base = row_base[z];
  int t = threadIdx.x;
  float a0 = 0.f, a1 = 0.f, a2 = 0.f, a3 = 0.f;
  for (int r = 0; r < n; r++) {
    ushort4 h = ((const ushort4*)(xhi + (size_t)(base + r) * 1024))[t];
    ushort4 l = ((const ushort4*)(xlo + (size_t)(base + r) * 1024))[t];
    a0 += bf2f(h.x) + bf2f(l.x); a1 += bf2f(h.y) + bf2f(l.y);
    a2 += bf2f(h.z) + bf2f(l.z); a3 += bf2f(h.w) + bf2f(l.w);
  }
  float4 o = make_float4(a0, a1, a2, a3);
  ((float4*)(xsum + (size_t)li * 1024))[t] = o;
}

// ksum[li][d] = sum_h Wk[e][d][h]*xsum[li][h] + n*bk[e][d]
__global__ __launch_bounds__(256) void k_kmv1b(const float* __restrict__ qkvw, const float* __restrict__ qkvb,
                                               const float* __restrict__ xsum, const int* __restrict__ cnt,
                                               float* __restrict__ ksum) {
  int ei = blockIdx.x;
  int e = ei * 4;
  int dblk = blockIdx.y;
  __shared__ float xs[4][1024];
  for (int i = threadIdx.x; i < 4096; i += 256) {
    int sl = i >> 10, h = i & 1023;
    xs[sl][h] = xsum[(size_t)(ei*4 + sl) * 1024 + h];
  }
  __syncthreads();
  int d_loc = threadIdx.x >> 3, hc = threadIdx.x & 7;
  int d = dblk * 32 + d_loc;
  const float* wrow = qkvw + ((size_t)e * 3072 + 1024 + d) * 1024;
  float a0 = 0.f, a1 = 0.f, a2 = 0.f, a3 = 0.f;
  for (int j = 0; j < 8; j++) {
    int h0 = j * 128 + hc * 16;
#pragma unroll
    for (int q = 0; q < 4; q++) {
      float4 wv = *(const float4*)(wrow + h0 + q*4);
#pragma unroll
      for (int b = 0; b < 4; b++) {
        float wf = (b == 0) ? wv.x : (b == 1) ? wv.y : (b == 2) ? wv.z : wv.w;
        int h = h0 + q*4 + b;
        a0 += wf * xs[0][h]; a1 += wf * xs[1][h];
        a2 += wf * xs[2][h]; a3 += wf * xs[3][h];
      }
    }
  }
  for (int m = 1; m < 8; m <<= 1) {
    a0 += __shfl_xor(a0, m); a1 += __shfl_xor(a1, m);
    a2 += __shfl_xor(a2, m); a3 += __shfl_xor(a3, m);
  }
  if (hc == 0) {
    float bk = qkvb[(size_t)e * 3072 + 1024 + d];
#pragma unroll
    for (int sl = 0; sl < 4; sl++) {
      float n = (float)cnt[ei * 16 + sl];
      float v = (sl == 0) ? a0 : (sl == 1) ? a1 : (sl == 2) ? a2 : a3;
      ksum[(size_t)(ei*4 + sl) * 1024 + d] = v + n * bk;
    }
  }
}

__global__ __launch_bounds__(256) void k_kmv2b(const float* __restrict__ qkvw, const float* __restrict__ ksum,
                                               float* __restrict__ upart) {
  int ei = blockIdx.x;
  int hb = blockIdx.y;
  int dc = blockIdx.z;
  int e = ei * 4;
  __shared__ float ks[4][128];
  for (int i = threadIdx.x; i < 512; i += 256) {
    int sl = i >> 7, d = i & 127;
    ks[sl][d] = ksum[(size_t)(ei*4 + sl) * 1024 + dc*128 + d];
  }
  __syncthreads();
  int h = hb * 256 + threadIdx.x;
  float a0 = 0.f, a1 = 0.f, a2 = 0.f, a3 = 0.f;
  const float* wq = qkvw + (size_t)e * 3072 * 1024 + (size_t)(dc * 128) * 1024 + h;
  for (int d = 0; d < 128; d++) {
    float wf = wq[(size_t)d * 1024];
    a0 += wf * ks[0][d]; a1 += wf * ks[1][d];
    a2 += wf * ks[2][d]; a3 += wf * ks[3][d];
  }
  size_t ob = (size_t)(ei*8 + dc) * 4096;
  upart[ob + 0*1024 + h] = a0;
  upart[ob + 1*1024 + h] = a1;
  upart[ob + 2*1024 + h] = a2;
  upart[ob + 3*1024 + h] = a3;
}

__global__ __launch_bounds__(256) void k_kmv2r(const float* __restrict__ upart, float* __restrict__ uvec) {
  int li = blockIdx.x;
  int ei = li >> 2, sl = li & 3;
  int h = blockIdx.y * 256 + threadIdx.x;
  float a = 0.f;
  for (int dc = 0; dc < 8; dc++)
    a += upart[(size_t)(ei*8 + dc) * 4096 + (size_t)sl * 1024 + h];
  uvec[(size_t)li * 1024 + h] = a;
}

__global__ __launch_bounds__(256) void k_cdot(const float* __restrict__ qkvb, const float* __restrict__ ksum,
                                              float* __restrict__ cvec) {
  int li = blockIdx.x;
  int e = (li >> 2) * 4;
  const float* bq = qkvb + (size_t)e * 3072;
  const float* ks = ksum + (size_t)li * 1024;
  float acc = 0.f;
  for (int d = threadIdx.x; d < 1024; d += 256) acc += bq[d] * ks[d];
  __shared__ float red[256];
  red[threadIdx.x] = acc;
  __syncthreads();
  for (int s = 128; s > 0; s >>= 1) {
    if (threadIdx.x < s) red[threadIdx.x] += red[threadIdx.x + s];
    __syncthreads();
  }
  if (threadIdx.x == 0) cvec[li] = red[0];
}

__global__ __launch_bounds__(256) void k_denom(const ushort* __restrict__ xhi, const ushort* __restrict__ xlo,
                                               const float* __restrict__ uvec, const float* __restrict__ cvec,
                                               const int* __restrict__ row_base, const int* __restrict__ cnt,
                                               float* __restrict__ denomArr) {
  int li = blockIdx.y;
  int z = (li >> 2) * 16 + (li & 3);
  int n = cnt[z], base = row_base[z];
  int g = threadIdx.x >> 5, lane = threadIdx.x & 31;
  int r = blockIdx.x * 8 + g;
  if (r >= n) return;
  const ushort* xh = xhi + (size_t)(base + r) * 1024;
  const ushort* xl = xlo + (size_t)(base + r) * 1024;
  const float* u = uvec + (size_t)li * 1024;
  float dn = 0.f;
  for (int j = 0; j < 32; j++) {
    int h = lane + j * 32;
    dn += (bf2f(xh[h]) + bf2f(xl[h])) * u[h];
  }
  dn += __shfl_xor(dn, 1); dn += __shfl_xor(dn, 2); dn += __shfl_xor(dn, 4);
  dn += __shfl_xor(dn, 8); dn += __shfl_xor(dn, 16);
  if (lane == 0) denomArr[base + r] = dn + cvec[li];
}

// ---------------- K6a: MFMA flash attention (standard experts) ----------------
__global__ __launch_bounds__(256) void k_attn_std(const ushort* __restrict__ qkv,
                                                  ushort* __restrict__ ahi, ushort* __restrict__ alo,
                                                  const int* __restrict__ row_base, const int* __restrict__ cnt,
                                                  const int* __restrict__ meta) {
  int z = blockIdx.z;
  int e = z >> 2;
  if ((e & 3) == 0) return;
  int n = cnt[z];
  int q0 = blockIdx.x * 64;
  if (q0 >= n) return;
  int h = blockIdx.y;
  int base = row_base[z];
  int tot = meta[0];

  __shared__ ushort Kb[32*264];
  __shared__ ushort Vt[256*40];
  __shared__ ushort Pb[4*16*40];

  int tid = threadIdx.x;
  int lane = tid & 63, w = tid >> 6;
  int lr = lane & 15, lk = lane >> 4;

  int qrow = base + q0 + w*16 + lr;
  const ushort* qptr = qkv + (size_t)min(qrow, tot - 1) * 3072 + h*256 + lk*8;
  short8 qf[8];
#pragma unroll
  for (int f = 0; f < 8; f++) qf[f] = *(const short8*)(qptr + f*32);

  f32x4 Oacc[16];
#pragma unroll
  for (int db = 0; db < 16; db++) Oacc[db] = (f32x4){0.f, 0.f, 0.f, 0.f};
  float m_run[4], l_run[4];
#pragma unroll
  for (int g = 0; g < 4; g++) { m_run[g] = -3e38f; l_run[g] = 0.f; }

  int ntile = (n + 31) >> 5;
  for (int t = 0; t < ntile; t++) {
    __syncthreads();
    for (int s = tid; s < 1024; s += 256) {
      int key = s >> 5, ch = s & 31;
      int krow = t*32 + key;
      short8 v = {0,0,0,0,0,0,0,0};
      if (krow < n) v = *(const short8*)(qkv + (size_t)(base + krow)*3072 + 1024 + h*256 + ch*8);
      *(short8*)(Kb + key*264 + ch*8) = v;
    }
    {
      int k2 = tid >> 3, dg = tid & 7;
      bool kval = (t*32 + k2) < n;
      const ushort* vsrc = qkv + (size_t)(base + min(t*32 + k2, n - 1))*3072 + 2048 + h*256 + dg*8;
#pragma unroll
      for (int tt = 0; tt < 4; tt++) {
        int dd = dg*8 + tt*64;
        short8 v = {0,0,0,0,0,0,0,0};
        if (kval) v = *(const short8*)(vsrc + tt*64);
#pragma unroll
        for (int j = 0; j < 8; j++) Vt[(dd + j)*40 + k2] = ((ushort*)&v)[j];
      }
    }
    __syncthreads();
    f32x4 S0 = (f32x4){0.f,0.f,0.f,0.f}, S1 = (f32x4){0.f,0.f,0.f,0.f};
#pragma unroll
    for (int db = 0; db < 8; db++) {
      short8 b0 = *(const short8*)(Kb + lr*264 + db*32 + lk*8);
      short8 b1 = *(const short8*)(Kb + (16 + lr)*264 + db*32 + lk*8);
      S0 = __builtin_amdgcn_mfma_f32_16x16x32_bf16(qf[db], b0, S0, 0, 0, 0);
      S1 = __builtin_amdgcn_mfma_f32_16x16x32_bf16(qf[db], b1, S1, 0, 0, 0);
    }
    bool v0 = (t*32 + lr) < n, v1 = (t*32 + 16 + lr) < n;
    float p0v[4], p1v[4], scv[4];
#pragma unroll
    for (int g = 0; g < 4; g++) {
      float s0 = v0 ? S0[g] * 0.0625f : -1e9f;
      float s1 = v1 ? S1[g] * 0.0625f : -1e9f;
      float mx = fmaxf(s0, s1);
      mx = fmaxf(mx, __shfl_xor(mx, 1)); mx = fmaxf(mx, __shfl_xor(mx, 2));
      mx = fmaxf(mx, __shfl_xor(mx, 4)); mx = fmaxf(mx, __shfl_xor(mx, 8));
      float nm = fmaxf(m_run[g], mx);
      float sc = __expf(m_run[g] - nm);
      m_run[g] = nm;
      float p0 = __expf(s0 - nm), p1 = __expf(s1 - nm);
      float sum = p0 + p1;
      sum += __shfl_xor(sum, 1); sum += __shfl_xor(sum, 2);
      sum += __shfl_xor(sum, 4); sum += __shfl_xor(sum, 8);
      l_run[g] = l_run[g] * sc + sum;
      p0v[g] = p0; p1v[g] = p1; scv[g] = sc;
    }
#pragma unroll
    for (int db = 0; db < 16; db++)
#pragma unroll
      for (int g = 0; g < 4; g++) Oacc[db][g] *= scv[g];
    ushort* pw = Pb + w*640;
#pragma unroll
    for (int g = 0; g < 4; g++) {
      int q = lk*4 + g;
      pw[q*40 + lr] = f2bf(p0v[g]);
      pw[q*40 + 16 + lr] = f2bf(p1v[g]);
    }
    __syncthreads();
    short8 pa = *(const short8*)(pw + lr*40 + lk*8);
#pragma unroll
    for (int db = 0; db < 16; db++) {
      short8 vb = *(const short8*)(Vt + (db*16 + lr)*40 + lk*8);
      Oacc[db] = __builtin_amdgcn_mfma_f32_16x16x32_bf16(pa, vb, Oacc[db], 0, 0, 0);
    }
  }
#pragma unroll
  for (int g = 0; g < 4; g++) {
    int qr = q0 + w*16 + lk*4 + g;
    if (qr < n) {
      float inv = 1.f / l_run[g];
      size_t ro = (size_t)(base + qr) * 1024 + h*256;
#pragma unroll
      for (int db = 0; db < 16; db++) {
        float v = Oacc[db][g] * inv;
        ushort hh, ll; split2(v, hh, ll);
        ahi[ro + db*16 + lr] = hh;
        alo[ro + db*16 + lr] = ll;
      }
    }
  }
}

// ---------------- K6b-A: linear attention S = Q.K^T (MFMA) ----------------
__global__ __launch_bounds__(256) void k_lin_qkt(const ushort* __restrict__ qkv,
                                                 ushort* __restrict__ Shi, ushort* __restrict__ Slo,
                                                 const int* __restrict__ row_base, const int* __restrict__ cnt) {
  int li = blockIdx.z;
  int z = (li >> 2) * 16 + (li & 3);
  int n = cnt[z];
  int q0 = blockIdx.y * 128, k0 = blockIdx.x * 128;
  if (q0 >= n || k0 >= n) return;
  int base = row_base[z];
  __shared__ ushort lds[2][128*32];
  int tid = threadIdx.x;
  int lane = tid & 63, w = tid >> 6;
  int wr = w >> 1, wc = w & 1;
  int lr = lane & 15, lk = lane >> 4;
  f32x4 acc[4][4] = {};
  int r0 = tid >> 2;
  int kc = (tid & 3) << 3;
  size_t a0 = (size_t)(base + min(q0 + r0, n - 1)) * 3072 + kc;
  size_t a1 = (size_t)(base + min(q0 + 64 + r0, n - 1)) * 3072 + kc;
  size_t b0 = (size_t)(base + min(k0 + r0, n - 1)) * 3072 + 1024 + kc;
  size_t b1 = (size_t)(base + min(k0 + 64 + r0, n - 1)) * 3072 + 1024 + kc;
  uint d0 = (uint)tid * 8, d1 = (uint)(256 + tid) * 8;
  for (int kb = 0; kb < 1024; kb += 32) {
    gload16(qkv + a0 + kb, &lds[0][d0]);
    gload16(qkv + a1 + kb, &lds[0][d1]);
    gload16(qkv + b0 + kb, &lds[1][d0]);
    gload16(qkv + b1 + kb, &lds[1][d1]);
    __syncthreads();
    short8 af[4], bf[4];
#pragma unroll
    for (int m = 0; m < 4; m++) af[m] = *(const short8*)&lds[0][(wr*64 + m*16 + lr)*32 + lk*8];
#pragma unroll
    for (int n2 = 0; n2 < 4; n2++) bf[n2] = *(const short8*)&lds[1][(wc*64 + n2*16 + lr)*32 + lk*8];
#pragma unroll
    for (int m = 0; m < 4; m++)
#pragma unroll
      for (int n2 = 0; n2 < 4; n2++)
        acc[m][n2] = __builtin_amdgcn_mfma_f32_16x16x32_bf16(af[m], bf[n2], acc[m][n2], 0, 0, 0);
    __syncthreads();
  }
#pragma unroll
  for (int n2 = 0; n2 < 4; n2++) {
    int col = k0 + wc*64 + n2*16 + lr;
#pragma unroll
    for (int m = 0; m < 4; m++) {
#pragma unroll
      for (int g = 0; g < 4; g++) {
        int row = q0 + wr*64 + m*16 + lk*4 + g;
        if (row < n) {
          float v = (col < n) ? acc[m][n2][g] : 0.f;
          ushort hh, ll; split2(v, hh, ll);
          size_t o = (size_t)li * (CAP*CAP) + (size_t)row * CAP + col;
          Shi[o] = hh; Slo[o] = ll;
        }
      }
    }
  }
}

// ---------------- K6b-B: linear attention O = (Shi+Slo).V * zq (MFMA) ----------------
__global__ __launch_bounds__(256) void k_lin_pv(const ushort* __restrict__ qkv,
                                                const ushort* __restrict__ Shi, const ushort* __restrict__ Slo,
                                                ushort* __restrict__ ahi, ushort* __restrict__ alo,
                                                const int* __restrict__ row_base, const int* __restrict__ cnt,
                                                const float* __restrict__ denomArr) {
  int li = blockIdx.y;
  int z = (li >> 2) * 16 + (li & 3);
  int n = cnt[z];
  int q0 = blockIdx.x * 64;
  if (q0 >= n) return;
  int base = row_base[z];
  __shared__ ushort Vt[256*40];
  int tid = threadIdx.x;
  int lane = tid & 63, w = tid >> 6;
  int lr = lane & 15, lk = lane >> 4;
  int ntile = (n + 31) >> 5;
  int k2 = tid >> 3, dg = tid & 7;
  int qrow = min(q0 + w*16 + lr, n - 1);
  const ushort* srowH = Shi + (size_t)li * (CAP*CAP) + (size_t)qrow * CAP;
  const ushort* srowL = Slo + (size_t)li * (CAP*CAP) + (size_t)qrow * CAP;
  for (int c = 0; c < 4; c++) {
    f32x4 Oacc[16];
#pragma unroll
    for (int db = 0; db < 16; db++) Oacc[db] = (f32x4){0.f, 0.f, 0.f, 0.f};
    for (int t = 0; t < ntile; t++) {
      __syncthreads();
      int krow = t*32 + k2;
      bool kval = krow < n;
      const ushort* vsrc = qkv + (size_t)(base + min(krow, n - 1))*3072 + 2048 + c*256 + dg*8;
#pragma unroll
      for (int tt = 0; tt < 4; tt++) {
        int dd = dg*8 + tt*64;
        short8 v = {0,0,0,0,0,0,0,0};
        if (kval) v = *(const short8*)(vsrc + tt*64);
#pragma unroll
        for (int j = 0; j < 8; j++) Vt[(dd + j)*40 + k2] = ((ushort*)&v)[j];
      }
      __syncthreads();
      short8 ph = *(const short8*)(srowH + t*32 + lk*8);
      short8 pl = *(const short8*)(srowL + t*32 + lk*8);
#pragma unroll
      for (int db = 0; db < 16; db++) {
        short8 vb = *(const short8*)(Vt + (db*16 + lr)*40 + lk*8);
        Oacc[db] = __builtin_amdgcn_mfma_f32_16x16x32_bf16(ph, vb, Oacc[db], 0, 0, 0);
        Oacc[db] = __builtin_amdgcn_mfma_f32_16x16x32_bf16(pl, vb, Oacc[db], 0, 0, 0);
      }
    }
#pragma unroll
    for (int g = 0; g < 4; g++) {
      int qr = q0 + w*16 + lk*4 + g;
      if (qr < n) {
        float zq = 1.f / (denomArr[base + qr] + 1e-6f);
        size_t ro = (size_t)(base + qr) * 1024 + c*256;
#pragma unroll
        for (int db = 0; db < 16; db++) {
          float v = Oacc[db][g] * zq;
          ushort hh, ll; split2(v, hh, ll);
          ahi[ro + db*16 + lr] = hh;
          alo[ro + db*16 + lr] = ll;
        }
      }
    }
  }
}

// ---------------- K11: weighted scatter ----------------
__global__ __launch_bounds__(256) void k_scatter(const float* __restrict__ o, const int* __restrict__ row_of,
                                                 const float* __restrict__ topw, float* __restrict__ out) {
  int t = blockIdx.x;
  float4 acc = make_float4(0.f, 0.f, 0.f, 0.f);
  for (int k = 0; k < TOPK; k++) {
    int row = row_of[t*TOPK + k];
    if (row >= 0) {
      float w = topw[t*TOPK + k];
      float4 v = ((const float4*)o)[(size_t)row * 256 + threadIdx.x];
      acc.x += w * v.x; acc.y += w * v.y; acc.z += w * v.z; acc.w += w * v.w;
    }
  }
  ((float4*)out)[(size_t)t * 256 + threadIdx.x] = acc;
}

extern "C" void kernel_launch(void* const* d_in, const int* in_sizes, int n_in,
                              void* d_out, int out_size, void* d_ws, size_t ws_size,
                              hipStream_t stream) {
  const float* x    = (const float*)d_in[0];
  const float* rw   = (const float*)d_in[1];
  const float* qkvw = (const float*)d_in[2];
  const float* qkvb = (const float*)d_in[3];
  const float* sww  = (const float*)d_in[4];
  const float* swb  = (const float*)d_in[5];
  const float* svw  = (const float*)d_in[6];
  const float* svb  = (const float*)d_in[7];
  const float* pjw  = (const float*)d_in[8];
  const float* pjb  = (const float*)d_in[9];
  float* out = (float*)d_out;

  char* ws = (char*)d_ws;
  const size_t MB = 1ull << 20;
  // Buffer lifetime map (no writer/reader overlap within any dispatch):
  //   xhi/xlo   [0,64)MB    : written by gather; read by qkv GEMM, xsum, denom.  DEAD after qkv GEMM.
  //   qkvB      [64,160)MB  : written by qkv GEMM; read by attn/lin.             DEAD after lin_pv.
  //   ahi/alo   [160,224)MB : written by attn + lin_pv; read by fused sw GEMM.
  //   Shi/Slo   [224,256)MB : written by lin_qkt; read by lin_pv.                DEAD after lin_pv.
  //   ghi/glo   [0,64)MB    : written by fused sw GEMM (xhi/xlo region);  read by sv GEMM.
  //   shi/slo   [224,288)MB : written by sv GEMM (Shi/Slo region);        read by proj GEMM.
  //   obuf      [64,128)MB  : written by proj GEMM (qkvB region);         read by scatter.
  ushort* xhi  = (ushort*)(ws + 0);
  ushort* xlo  = (ushort*)(ws + 32*MB);
  ushort* qkvB = (ushort*)(ws + 64*MB);
  ushort* ahi  = (ushort*)(ws + 160*MB);
  ushort* alo  = (ushort*)(ws + 192*MB);
  ushort* Shi  = (ushort*)(ws + 224*MB);
  ushort* Slo  = (ushort*)(ws + 240*MB);
  ushort* ghi  = (ushort*)(ws + 0);
  ushort* glo  = (ushort*)(ws + 32*MB);
  ushort* shi  = (ushort*)(ws + 224*MB);
  ushort* slo  = (ushort*)(ws + 256*MB);
  float*  obuf = (float*)(ws + 64*MB);
  char* sm = ws + 288*MB;
  size_t off = 0;
  auto alloc = [&](size_t bytes) { char* p = sm + off; off += (bytes + 255) & ~(size_t)255; return p; };
  int*   topi = (int*)alloc(T_TOK*TOPK*4);
  float* topw = (float*)alloc(T_TOK*TOPK*4);
  int*   pos  = (int*)alloc(T_TOK*TOPK*4);
  int*   rof  = (int*)alloc(T_TOK*TOPK*4);
  int*   craw = (int*)alloc(NEXP*TOPK*4);
  int*   cnt  = (int*)alloc(NEXP*TOPK*4);
  int*   rbase= (int*)alloc(NEXP*TOPK*4);
  int*   meta = (int*)alloc(256);
  float* xsum = (float*)alloc(32*1024*4);
  float* ksum = (float*)alloc(32*1024*4);
  float* uvec = (float*)alloc(32*1024*4);
  float* cvec = (float*)alloc(32*4);
  float* denomArr = (float*)alloc(MAXROWS*4);
  float* upart = (float*)alloc(8*8*4*1024*4);

  k_router <<<T_TOK, 256, 0, stream>>>(x, rw, topi, topw);
  k_scan   <<<NEXP*TOPK, 256, 0, stream>>>(topi, pos, craw);
  k_offsets<<<1, 64, 0, stream>>>(craw, cnt, rbase, meta);
  k_gather <<<T_TOK*TOPK, 256, 0, stream>>>(x, topi, pos, rbase, rof, xhi, xlo);

  // exact f32 denominator bypass (linear experts)
  k_xsum  <<<32, 256, 0, stream>>>(xhi, xlo, rbase, cnt, xsum);
  k_kmv1b <<<dim3(8, 32), 256, 0, stream>>>(qkvw, qkvb, xsum, cnt, ksum);
  k_kmv2b <<<dim3(8, 4, 8), 256, 0, stream>>>(qkvw, ksum, upart);
  k_kmv2r <<<dim3(32, 4), 256, 0, stream>>>(upart, uvec);
  k_cdot  <<<32, 256, 0, stream>>>(qkvb, ksum, cvec);
  k_denom <<<dim3(64, 32), 256, 0, stream>>>(xhi, xlo, uvec, cvec, rbase, cnt, denomArr);

  // qkv GEMM -> bf16 (R8-proven structure)
  dim3 gqkv(3072/128, 16, NEXP);
  k_mfma_gemm<1><<<gqkv, 256, 0, stream>>>(xhi, xlo, qkvw, qkvb, 3072, 0,
                                           nullptr, qkvB, nullptr, 3072, rbase, cnt, meta);

  dim3 ga(CAP/64, NH, NEXP*TOPK);
  k_attn_std<<<ga, 256, 0, stream>>>(qkvB, ahi, alo, rbase, cnt, meta);
  dim3 gq(CAP/128, CAP/128, 32);
  k_lin_qkt<<<gq, 256, 0, stream>>>(qkvB, Shi, Slo, rbase, cnt);
  dim3 gp(CAP/64, 32);
  k_lin_pv<<<gp, 256, 0, stream>>>(qkvB, Shi, Slo, ahi, alo, rbase, cnt, denomArr);

  // sw GEMM with fused SwiGLU epilogue -> g planes (xhi/xlo region; NOT aliasing ahi/alo)
  dim3 gsw(1024/64, 16, NEXP);
  k_mfma_gemm<3><<<gsw, 256, 0, stream>>>(ahi, alo, sww, swb, 2048, 0,
                                          nullptr, ghi, glo, 1024, rbase, cnt, meta);

  dim3 g1k(1024/128, 16, NEXP);
  k_mfma_gemm<2><<<g1k, 256, 0, stream>>>(ghi, glo, svw, svb, 1024, 0,
                                          nullptr, shi, slo, 1024, rbase, cnt, meta);
  k_mfma_gemm<0><<<g1k, 256, 0, stream>>>(shi, slo, pjw, pjb, 1024, 0,
                                          obuf, nullptr, nullptr, 1024, rbase, cnt, meta);

  k_scatter<<<T_TOK, 256, 0, stream>>>(obuf, rof, topw, out);
}

// Round 14
// 1497.505 us; speedup vs baseline: 1.5700x; 1.0131x over previous
//
#include <hip/hip_runtime.h>
#include <hip/hip_bf16.h>
#include <cstdint>

#define T_TOK 4096
#define NEXP  32
#define TOPK  4
#define CAP   512
#define H     1024
#define E     1024
#define NH    4
#define HD    256
#define MAXROWS (T_TOK*TOPK)   // 16384

typedef __attribute__((ext_vector_type(4))) float f32x4;
typedef __attribute__((ext_vector_type(8))) short short8;

__device__ __forceinline__ float bf2f(ushort u) {
  return __uint_as_float(((uint)u) << 16);
}
__device__ __forceinline__ ushort f2bf(float f) {
  uint u = __float_as_uint(f);
  uint r = (u + 0x7fffu + ((u >> 16) & 1u)) >> 16;
  return (ushort)r;
}
__device__ __forceinline__ void split2(float v, ushort& h, ushort& l) {
  h = f2bf(v);
  l = f2bf(v - bf2f(h));
}
__device__ __forceinline__ void gload16(const void* g, void* l) {
  __builtin_amdgcn_global_load_lds((const __attribute__((address_space(1))) void*)g,
                                   (__attribute__((address_space(3))) void*)l, 16, 0, 0);
}

// packed f32 pair -> (hi bf16x2, lo bf16x2); RNE, bit-identical to split2
#define CVTPK(F0, F1, HP, LP) do { \
  asm("v_cvt_pk_bf16_f32 %0, %1, %2" : "=v"(HP) : "v"(F0), "v"(F1)); \
  float _h0 = __uint_as_float((HP) << 16); \
  float _h1 = __uint_as_float((HP) & 0xffff0000u); \
  float _l0 = (F0) - _h0, _l1 = (F1) - _h1; \
  asm("v_cvt_pk_bf16_f32 %0, %1, %2" : "=v"(LP) : "v"(_l0), "v"(_l1)); \
} while (0)

// ---------------- K1: router ----------------
__global__ __launch_bounds__(256) void k_router(const float* __restrict__ x, const float* __restrict__ rw,
                                                int* __restrict__ topi, float* __restrict__ topw) {
  int t = blockIdx.x;
  __shared__ float4 xs[256];
  __shared__ float lg[NEXP];
  const float4* xr = (const float4*)(x + (size_t)t * H);
  xs[threadIdx.x] = xr[threadIdx.x];
  __syncthreads();
  int g = threadIdx.x >> 3, s = threadIdx.x & 7;
  const float4* wr = (const float4*)(rw + (size_t)g * H);
  float acc = 0.f;
  for (int j = s; j < 256; j += 8) {
    float4 a = xs[j], b = wr[j];
    acc += a.x * b.x + a.y * b.y + a.z * b.z + a.w * b.w;
  }
  acc += __shfl_xor(acc, 1);
  acc += __shfl_xor(acc, 2);
  acc += __shfl_xor(acc, 4);
  if (s == 0) lg[g] = acc;
  __syncthreads();
  if (threadIdx.x == 0) {
    float mx = -3e38f;
    for (int j = 0; j < NEXP; j++) mx = fmaxf(mx, lg[j]);
    float p[NEXP]; float sum = 0.f;
    for (int j = 0; j < NEXP; j++) { p[j] = __expf(lg[j] - mx); sum += p[j]; }
    float inv = 1.f / sum;
    int idx[TOPK]; float val[TOPK];
    for (int k = 0; k < TOPK; k++) {
      int best = 0; float bv = -1.f;
      for (int j = 0; j < NEXP; j++) if (p[j] > bv) { bv = p[j]; best = j; }
      idx[k] = best; val[k] = bv * inv; p[best] = -2.f;
    }
    float wsn = val[0] + val[1] + val[2] + val[3] + 1e-6f;
    for (int k = 0; k < TOPK; k++) { topi[t*TOPK + k] = idx[k]; topw[t*TOPK + k] = val[k] / wsn; }
  }
}

// ---------------- K2: rank scan ----------------
__global__ __launch_bounds__(256) void k_scan(const int* __restrict__ topi, int* __restrict__ pos_arr,
                                              int* __restrict__ cnt_raw) {
  int p = blockIdx.x;
  int e = p >> 2, kk = p & 3;
  __shared__ int wtot[4];
  int lane = threadIdx.x & 63, wid = threadIdx.x >> 6;
  int base = 0;
  for (int t0 = 0; t0 < T_TOK; t0 += 256) {
    int t = t0 + threadIdx.x;
    bool flag = (topi[t*TOPK + kk] == e);
    unsigned long long m = __ballot(flag);
    int excl = __popcll(m & ((1ull << lane) - 1ull));
    if (lane == 0) wtot[wid] = __popcll(m);
    __syncthreads();
    int wexcl = 0, tot = 0;
#pragma unroll
    for (int w2 = 0; w2 < 4; w2++) { int v = wtot[w2]; if (w2 < wid) wexcl += v; tot += v; }
    if (flag) pos_arr[t*TOPK + kk] = base + wexcl + excl;
    base += tot;
    __syncthreads();
  }
  if (threadIdx.x == 0) cnt_raw[p] = base;
}

// ---------------- K3: offsets ----------------
__global__ void k_offsets(const int* __restrict__ cnt_raw, int* __restrict__ cnt,
                          int* __restrict__ row_base, int* __restrict__ meta) {
  if (threadIdx.x == 0 && blockIdx.x == 0) {
    int acc = 0;
    for (int p = 0; p < NEXP*TOPK; p++) {
      int c = cnt_raw[p]; if (c > CAP) c = CAP;
      cnt[p] = c; row_base[p] = acc; acc += c;
    }
    meta[0] = acc;
  }
}

// ---------------- K4: gather -> hi/lo planes ----------------
__global__ __launch_bounds__(256) void k_gather(const float* __restrict__ x, const int* __restrict__ topi,
                                                const int* __restrict__ pos_arr, const int* __restrict__ row_base,
                                                int* __restrict__ row_of, ushort* __restrict__ xhi, ushort* __restrict__ xlo) {
  int b = blockIdx.x;
  int t = b >> 2, kk = b & 3;
  int e = topi[b];
  int pos = pos_arr[b];
  int row = (pos < CAP) ? (row_base[e*TOPK + kk] + pos) : -1;
  if (threadIdx.x == 0) row_of[b] = row;
  if (row >= 0) {
    float4 v = ((const float4*)x)[(size_t)t * 256 + threadIdx.x];
    ushort4 h, l;
    split2(v.x, h.x, l.x); split2(v.y, h.y, l.y);
    split2(v.z, h.z, l.z); split2(v.w, h.w, l.w);
    ((ushort4*)xhi)[(size_t)row * 256 + threadIdx.x] = h;
    ((ushort4*)xlo)[(size_t)row * 256 + threadIdx.x] = l;
  }
}

// ---------------- split-bf16 MFMA segment GEMM (128x128 tile, W read directly as f32) ----------------
// C[r, colG] = A[r,:1024] @ W_e[colG,:1024]^T + bias (R8-proven structure).
// OMODE: 0 = f32 out, 1 = bf16 out, 2 = hi/lo plane out,
//        3 = fused SwiGLU: block covers 64 g-cols; stages 64 u-rows + 64 gate-rows of W;
//            epilogue exchanges gate accs via LDS and writes g = u*silu(gate) hi/lo planes.
//            NOTE: OMODE3 output buffers must NOT alias the A input (cross-block race).
template<int OMODE>
__global__ __launch_bounds__(256) void k_mfma_gemm(
    const ushort* __restrict__ Ahi, const ushort* __restrict__ Alo,
    const float* __restrict__ W, const float* __restrict__ Bias, int Ntot, int n0c,
    float* __restrict__ Cf, ushort* __restrict__ Chi, ushort* __restrict__ Clo, int ldc,
    const int* __restrict__ row_base, const int* __restrict__ cnt, const int* __restrict__ meta) {
  int e = blockIdx.z;
  int rs = row_base[e*4];
  int re = row_base[e*4 + 3] + cnt[e*4 + 3];
  int m0 = rs + blockIdx.y * 128;
  if (m0 >= re) return;
  int nb = (OMODE == 3) ? blockIdx.x * 64 : blockIdx.x * 128;  // OMODE3: g-col base
  int tot = meta[0];
  __shared__ __align__(16) char smem[32768];
  ushort* ldsA0 = (ushort*)smem;             // 8 KB: A hi, XOR-4 swizzled slots
  ushort* ldsA1 = (ushort*)(smem + 8192);    // 8 KB: A lo
  float*  ldsW  = (float*)(smem + 16384);    // 16 KB: W f32, XOR-8 swizzled slots
  int tid = threadIdx.x;
  int lane = tid & 63, w = tid >> 6;
  int wr = w >> 1, wc = w & 1;
  int lr = lane & 15, lk = lane >> 4;
  f32x4 acc[4][4] = {};

  int r0 = tid >> 2;
  int gA = (tid >> 3) & 3;
  int kc = (((tid & 3) ^ gA)) << 3;
  size_t a_off0 = (size_t)min(m0 + r0, tot - 1) * 1024 + kc;
  size_t a_off1 = (size_t)min(m0 + 64 + r0, tot - 1) * 1024 + kc;
  uint d0 = (uint)tid * 8, d1 = (uint)(256 + tid) * 8;

  const float* wsrc0; const float* wsrc1; const float* wsrc2; const float* wsrc3;
  {
    auto wrow = [&](int rr) -> int {
      if (OMODE == 3) return (rr < 64) ? (nb + rr) : (1024 + nb + (rr - 64));
      return n0c + nb + rr;
    };
    int i0 = tid;           int rr0 = i0 >> 3, c0 = (i0 & 7) ^ (rr0 & 7);
    int i1 = tid + 256;     int rr1 = i1 >> 3, c1 = (i1 & 7) ^ (rr1 & 7);
    int i2 = tid + 512;     int rr2 = i2 >> 3, c2 = (i2 & 7) ^ (rr2 & 7);
    int i3 = tid + 768;     int rr3 = i3 >> 3, c3 = (i3 & 7) ^ (rr3 & 7);
    wsrc0 = W + ((size_t)e * Ntot + wrow(rr0)) * 1024 + c0 * 4;
    wsrc1 = W + ((size_t)e * Ntot + wrow(rr1)) * 1024 + c1 * 4;
    wsrc2 = W + ((size_t)e * Ntot + wrow(rr2)) * 1024 + c2 * 4;
    wsrc3 = W + ((size_t)e * Ntot + wrow(rr3)) * 1024 + c3 * 4;
  }

  for (int kb = 0; kb < 1024; kb += 32) {
    gload16(Ahi + a_off0 + kb, &ldsA0[d0]);
    gload16(Ahi + a_off1 + kb, &ldsA0[d1]);
    gload16(Alo + a_off0 + kb, &ldsA1[d0]);
    gload16(Alo + a_off1 + kb, &ldsA1[d1]);
    gload16(wsrc0 + kb, &ldsW[(uint)tid * 4]);
    gload16(wsrc1 + kb, &ldsW[(uint)(tid + 256) * 4]);
    gload16(wsrc2 + kb, &ldsW[(uint)(tid + 512) * 4]);
    gload16(wsrc3 + kb, &ldsW[(uint)(tid + 768) * 4]);
    __syncthreads();
    short8 ah[4], al[4], bh[4], bl[4];
#pragma unroll
    for (int m = 0; m < 4; m++) {
      int rA = wr*64 + m*16 + lr;
      int sA = (lk ^ ((rA >> 1) & 3)) << 3;
      ah[m] = *(const short8*)&ldsA0[rA*32 + sA];
      al[m] = *(const short8*)&ldsA1[rA*32 + sA];
    }
#pragma unroll
    for (int n = 0; n < 4; n++) {
      int rB = wc*64 + n*16 + lr;
      int x7 = rB & 7;
      float4 w0 = *(const float4*)&ldsW[rB*32 + (((lk*2)     ^ x7) << 2)];
      float4 w1 = *(const float4*)&ldsW[rB*32 + (((lk*2 + 1) ^ x7) << 2)];
      uint hp0, hp1, hp2, hp3, lp0, lp1, lp2, lp3;
      CVTPK(w0.x, w0.y, hp0, lp0);
      CVTPK(w0.z, w0.w, hp1, lp1);
      CVTPK(w1.x, w1.y, hp2, lp2);
      CVTPK(w1.z, w1.w, hp3, lp3);
      uint4 hv = make_uint4(hp0, hp1, hp2, hp3);
      uint4 lv = make_uint4(lp0, lp1, lp2, lp3);
      bh[n] = __builtin_bit_cast(short8, hv);
      bl[n] = __builtin_bit_cast(short8, lv);
    }
#pragma unroll
    for (int m = 0; m < 4; m++)
#pragma unroll
      for (int n = 0; n < 4; n++) {
        acc[m][n] = __builtin_amdgcn_mfma_f32_16x16x32_bf16(ah[m], bh[n], acc[m][n], 0, 0, 0);
        acc[m][n] = __builtin_amdgcn_mfma_f32_16x16x32_bf16(ah[m], bl[n], acc[m][n], 0, 0, 0);
        acc[m][n] = __builtin_amdgcn_mfma_f32_16x16x32_bf16(al[m], bh[n], acc[m][n], 0, 0, 0);
      }
    __syncthreads();
  }

  if constexpr (OMODE == 3) {
    // gate waves (wc==1) publish acc+bias_gate via LDS; u waves apply silu and store planes
    float* gbuf = (float*)smem;   // 128 rows x 64 cols f32 = 32 KB (full smem alias)
    if (wc == 1) {
#pragma unroll
      for (int n = 0; n < 4; n++) {
        int colL = n*16 + lr;
        float bg = Bias[(size_t)e * Ntot + 1024 + nb + colL];
#pragma unroll
        for (int m = 0; m < 4; m++) {
#pragma unroll
          for (int g = 0; g < 4; g++) {
            int rowL = wr*64 + m*16 + lk*4 + g;
            gbuf[rowL*64 + colL] = acc[m][n][g] + bg;
          }
        }
      }
    }
    __syncthreads();
    if (wc == 0) {
#pragma unroll
      for (int n = 0; n < 4; n++) {
        int colL = n*16 + lr;
        int colG = nb + colL;
        float bu = Bias[(size_t)e * Ntot + colG];
#pragma unroll
        for (int m = 0; m < 4; m++) {
          int rb = m0 + wr*64 + m*16 + lk*4;
#pragma unroll
          for (int g = 0; g < 4; g++) {
            int r = rb + g;
            if (r < re) {
              int rowL = wr*64 + m*16 + lk*4 + g;
              float gate = gbuf[rowL*64 + colL];
              float u = acc[m][n][g] + bu;
              float gv = u * (gate / (1.f + __expf(-gate)));
              ushort hh, ll; split2(gv, hh, ll);
              Chi[(size_t)r * ldc + colG] = hh;
              Clo[(size_t)r * ldc + colG] = ll;
            }
          }
        }
      }
    }
    return;
  }

#pragma unroll
  for (int n = 0; n < 4; n++) {
    int colG = n0c + nb + wc*64 + n*16 + lr;
    float bi = Bias[(size_t)e * Ntot + colG];
#pragma unroll
    for (int m = 0; m < 4; m++) {
      int rb = m0 + wr*64 + m*16 + lk*4;
#pragma unroll
      for (int g = 0; g < 4; g++) {
        int r = rb + g;
        if (r < re) {
          float v = acc[m][n][g] + bi;
          if constexpr (OMODE == 0) {
            Cf[(size_t)r * ldc + colG] = v;
          } else if constexpr (OMODE == 1) {
            Chi[(size_t)r * ldc + colG] = f2bf(v);
          } else {
            ushort h, l; split2(v, h, l);
            Chi[(size_t)r * ldc + colG] = h;
            Clo[(size_t)r * ldc + colG] = l;
          }
        }
      }
    }
  }
}

// ---------------- exact f32 denominator bypass for linear experts ----------------
// parallelized column-sum: block (li, chunk of 64 rows) -> deterministic partials
__global__ __launch_bounds__(256) void k_xsum(const ushort* __restrict__ xhi, const ushort* __restrict__ xlo,
                                              const int* __restrict__ row_base, const int* __restrict__ cnt,
                                              float* __restrict__ xpart) {
  int li = blockIdx.x;          // 32
  int ch = blockIdx.y;          // 8 chunks x 64 rows
  int z = (li >> 2) * 16 + (li & 3);
  int n = cnt[z], base = row_base[z];
  int t = threadIdx.x;
  int rA = ch * 64, rB = min(rA + 64, n);
  float a0 = 0.f, a1 = 0.f, a2 = 0.f, a3 = 0.f;
  for (int r = rA; r < rB; r++) {
    ushort4 h = ((const ushort4*)(xhi + (size_t)(base + r) * 1024))[t];
    ushort4 l = ((const ushort4*)(xlo + (size_t)(base + r) * 1024))[t];
    a0 += bf2f(h.x) + bf2f(l.x); a1 += bf2f(h.y) + bf2f(l.y);
    a2 += bf2f(h.z) + bf2f(l.z); a3 += bf2f(h.w) + bf2f(l.w);
  }
  float4 o = make_float4(a0, a1, a2, a3);
  ((float4*)(xpart + ((size_t)li * 8 + ch) * 1024))[t] = o;
}

// ksum[li][d] = sum_h Wk[e][d][h]*xsum[li][h] + n*bk[e][d]  (xsum reduced inline from xpart)
__global__ __launch_bounds__(256) void k_kmv1b(const float* __restrict__ qkvw, const float* __restrict__ qkvb,
                                               const float* __restrict__ xpart, const int* __restrict__ cnt,
                                               float* __restrict__ ksum) {
  int ei = blockIdx.x;
  int e = ei * 4;
  int dblk = blockIdx.y;
  __shared__ float xs[4][1024];
  for (int i = threadIdx.x; i < 4096; i += 256) {
    int sl = i >> 10, h = i & 1023;
    const float* xp = xpart + ((size_t)(ei*4 + sl) * 8) * 1024 + h;
    float s = 0.f;
#pragma unroll
    for (int c = 0; c < 8; c++) s += xp[c * 1024];
    xs[sl][h] = s;
  }
  __syncthreads();
  int d_loc = threadIdx.x >> 3, hc = threadIdx.x & 7;
  int d = dblk * 32 + d_loc;
  const float* wrow = qkvw + ((size_t)e * 3072 + 1024 + d) * 1024;
  float a0 = 0.f, a1 = 0.f, a2 = 0.f, a3 = 0.f;
  for (int j = 0; j < 8; j++) {
    int h0 = j * 128 + hc * 16;
#pragma unroll
    for (int q = 0; q < 4; q++) {
      float4 wv = *(const float4*)(wrow + h0 + q*4);
#pragma unroll
      for (int b = 0; b < 4; b++) {
        float wf = (b == 0) ? wv.x : (b == 1) ? wv.y : (b == 2) ? wv.z : wv.w;
        int h = h0 + q*4 + b;
        a0 += wf * xs[0][h]; a1 += wf * xs[1][h];
        a2 += wf * xs[2][h]; a3 += wf * xs[3][h];
      }
    }
  }
  for (int m = 1; m < 8; m <<= 1) {
    a0 += __shfl_xor(a0, m); a1 += __shfl_xor(a1, m);
    a2 += __shfl_xor(a2, m); a3 += __shfl_xor(a3, m);
  }
  if (hc == 0) {
    float bk = qkvb[(size_t)e * 3072 + 1024 + d];
#pragma unroll
    for (int sl = 0; sl < 4; sl++) {
      float n = (float)cnt[ei * 16 + sl];
      float v = (sl == 0) ? a0 : (sl == 1) ? a1 : (sl == 2) ? a2 : a3;
      ksum[(size_t)(ei*4 + sl) * 1024 + d] = v + n * bk;
    }
  }
}

__global__ __launch_bounds__(256) void k_kmv2b(const float* __restrict__ qkvw, const float* __restrict__ ksum,
                                               float* __restrict__ upart) {
  int ei = blockIdx.x;
  int hb = blockIdx.y;
  int dc = blockIdx.z;
  int e = ei * 4;
  __shared__ float ks[4][128];
  for (int i = threadIdx.x; i < 512; i += 256) {
    int sl = i >> 7, d = i & 127;
    ks[sl][d] = ksum[(size_t)(ei*4 + sl) * 1024 + dc*128 + d];
  }
  __syncthreads();
  int h = hb * 256 + threadIdx.x;
  float a0 = 0.f, a1 = 0.f, a2 = 0.f, a3 = 0.f;
  const float* wq = qkvw + (size_t)e * 3072 * 1024 + (size_t)(dc * 128) * 1024 + h;
  for (int d = 0; d < 128; d++) {
    float wf = wq[(size_t)d * 1024];
    a0 += wf * ks[0][d]; a1 += wf * ks[1][d];
    a2 += wf * ks[2][d]; a3 += wf * ks[3][d];
  }
  size_t ob = (size_t)(ei*8 + dc) * 4096;
  upart[ob + 0*1024 + h] = a0;
  upart[ob + 1*1024 + h] = a1;
  upart[ob + 2*1024 + h] = a2;
  upart[ob + 3*1024 + h] = a3;
}

__global__ __launch_bounds__(256) void k_kmv2r(const float* __restrict__ upart, float* __restrict__ uvec) {
  int li = blockIdx.x;
  int ei = li >> 2, sl = li & 3;
  int h = blockIdx.y * 256 + threadIdx.x;
  float a = 0.f;
  for (int dc = 0; dc < 8; dc++)
    a += upart[(size_t)(ei*8 + dc) * 4096 + (size_t)sl * 1024 + h];
  uvec[(size_t)li * 1024 + h] = a;
}

__global__ __launch_bounds__(256) void k_cdot(const float* __restrict__ qkvb, const float* __restrict__ ksum,
                                              float* __restrict__ cvec) {
  int li = blockIdx.x;
  int e = (li >> 2) * 4;
  const float* bq = qkvb + (size_t)e * 3072;
  const float* ks = ksum + (size_t)li * 1024;
  float acc = 0.f;
  for (int d = threadIdx.x; d < 1024; d += 256) acc += bq[d] * ks[d];
  __shared__ float red[256];
  red[threadIdx.x] = acc;
  __syncthreads();
  for (int s = 128; s > 0; s >>= 1) {
    if (threadIdx.x < s) red[threadIdx.x] += red[threadIdx.x + s];
    __syncthreads();
  }
  if (threadIdx.x == 0) cvec[li] = red[0];
}

__global__ __launch_bounds__(256) void k_denom(const ushort* __restrict__ xhi, const ushort* __restrict__ xlo,
                                               const float* __restrict__ uvec, const float* __restrict__ cvec,
                                               const int* __restrict__ row_base, const int* __restrict__ cnt,
                                               float* __restrict__ denomArr) {
  int li = blockIdx.y;
  int z = (li >> 2) * 16 + (li & 3);
  int n = cnt[z], base = row_base[z];
  int g = threadIdx.x >> 5, lane = threadIdx.x & 31;
  int r = blockIdx.x * 8 + g;
  if (r >= n) return;
  const ushort* xh = xhi + (size_t)(base + r) * 1024;
  const ushort* xl = xlo + (size_t)(base + r) * 1024;
  const float* u = uvec + (size_t)li * 1024;
  float dn = 0.f;
  for (int j = 0; j < 32; j++) {
    int h = lane + j * 32;
    dn += (bf2f(xh[h]) + bf2f(xl[h])) * u[h];
  }
  dn += __shfl_xor(dn, 1); dn += __shfl_xor(dn, 2); dn += __shfl_xor(dn, 4);
  dn += __shfl_xor(dn, 8); dn += __shfl_xor(dn, 16);
  if (lane == 0) denomArr[base + r] = dn + cvec[li];
}

// ---------------- K6a: MFMA flash attention (standard experts) ----------------
__global__ __launch_bounds__(256) void k_attn_std(const ushort* __restrict__ qkv,
                                                  ushort* __restrict__ ahi, ushort* __restrict__ alo,
                                                  const int* __restrict__ row_base, const int* __restrict__ cnt,
                                                  const int* __restrict__ meta) {
  int z = blockIdx.z;
  int e = z >> 2;
  if ((e & 3) == 0) return;
  int n = cnt[z];
  int q0 = blockIdx.x * 64;
  if (q0 >= n) return;
  int h = blockIdx.y;
  int base = row_base[z];
  int tot = meta[0];

  __shared__ ushort Kb[32*264];
  __shared__ ushort Vt[256*40];
  __shared__ ushort Pb[4*16*40];

  int tid = threadIdx.x;
  int lane = tid & 63, w = tid >> 6;
  int lr = lane & 15, lk = lane >> 4;

  int qrow = base + q0 + w*16 + lr;
  const ushort* qptr = qkv + (size_t)min(qrow, tot - 1) * 3072 + h*256 + lk*8;
  short8 qf[8];
#pragma unroll
  for (int f = 0; f < 8; f++) qf[f] = *(const short8*)(qptr + f*32);

  f32x4 Oacc[16];
#pragma unroll
  for (int db = 0; db < 16; db++) Oacc[db] = (f32x4){0.f, 0.f, 0.f, 0.f};
  float m_run[4], l_run[4];
#pragma unroll
  for (int g = 0; g < 4; g++) { m_run[g] = -3e38f; l_run[g] = 0.f; }

  int ntile = (n + 31) >> 5;
  for (int t = 0; t < ntile; t++) {
    __syncthreads();
    for (int s = tid; s < 1024; s += 256) {
      int key = s >> 5, ch = s & 31;
      int krow = t*32 + key;
      short8 v = {0,0,0,0,0,0,0,0};
      if (krow < n) v = *(const short8*)(qkv + (size_t)(base + krow)*3072 + 1024 + h*256 + ch*8);
      *(short8*)(Kb + key*264 + ch*8) = v;
    }
    {
      int k2 = tid >> 3, dg = tid & 7;
      bool kval = (t*32 + k2) < n;
      const ushort* vsrc = qkv + (size_t)(base + min(t*32 + k2, n - 1))*3072 + 2048 + h*256 + dg*8;
#pragma unroll
      for (int tt = 0; tt < 4; tt++) {
        int dd = dg*8 + tt*64;
        short8 v = {0,0,0,0,0,0,0,0};
        if (kval) v = *(const short8*)(vsrc + tt*64);
#pragma unroll
        for (int j = 0; j < 8; j++) Vt[(dd + j)*40 + k2] = ((ushort*)&v)[j];
      }
    }
    __syncthreads();
    f32x4 S0 = (f32x4){0.f,0.f,0.f,0.f}, S1 = (f32x4){0.f,0.f,0.f,0.f};
#pragma unroll
    for (int db = 0; db < 8; db++) {
      short8 b0 = *(const short8*)(Kb + lr*264 + db*32 + lk*8);
      short8 b1 = *(const short8*)(Kb + (16 + lr)*264 + db*32 + lk*8);
      S0 = __builtin_amdgcn_mfma_f32_16x16x32_bf16(qf[db], b0, S0, 0, 0, 0);
      S1 = __builtin_amdgcn_mfma_f32_16x16x32_bf16(qf[db], b1, S1, 0, 0, 0);
    }
    bool v0 = (t*32 + lr) < n, v1 = (t*32 + 16 + lr) < n;
    float p0v[4], p1v[4], scv[4];
#pragma unroll
    for (int g = 0; g < 4; g++) {
      float s0 = v0 ? S0[g] * 0.0625f : -1e9f;
      float s1 = v1 ? S1[g] * 0.0625f : -1e9f;
      float mx = fmaxf(s0, s1);
      mx = fmaxf(mx, __shfl_xor(mx, 1)); mx = fmaxf(mx, __shfl_xor(mx, 2));
      mx = fmaxf(mx, __shfl_xor(mx, 4)); mx = fmaxf(mx, __shfl_xor(mx, 8));
      float nm = fmaxf(m_run[g], mx);
      float sc = __expf(m_run[g] - nm);
      m_run[g] = nm;
      float p0 = __expf(s0 - nm), p1 = __expf(s1 - nm);
      float sum = p0 + p1;
      sum += __shfl_xor(sum, 1); sum += __shfl_xor(sum, 2);
      sum += __shfl_xor(sum, 4); sum += __shfl_xor(sum, 8);
      l_run[g] = l_run[g] * sc + sum;
      p0v[g] = p0; p1v[g] = p1; scv[g] = sc;
    }
#pragma unroll
    for (int db = 0; db < 16; db++)
#pragma unroll
      for (int g = 0; g < 4; g++) Oacc[db][g] *= scv[g];
    ushort* pw = Pb + w*640;
#pragma unroll
    for (int g = 0; g < 4; g++) {
      int q = lk*4 + g;
      pw[q*40 + lr] = f2bf(p0v[g]);
      pw[q*40 + 16 + lr] = f2bf(p1v[g]);
    }
    __syncthreads();
    short8 pa = *(const short8*)(pw + lr*40 + lk*8);
#pragma unroll
    for (int db = 0; db < 16; db++) {
      short8 vb = *(const short8*)(Vt + (db*16 + lr)*40 + lk*8);
      Oacc[db] = __builtin_amdgcn_mfma_f32_16x16x32_bf16(pa, vb, Oacc[db], 0, 0, 0);
    }
  }
#pragma unroll
  for (int g = 0; g < 4; g++) {
    int qr = q0 + w*16 + lk*4 + g;
    if (qr < n) {
      float inv = 1.f / l_run[g];
      size_t ro = (size_t)(base + qr) * 1024 + h*256;
#pragma unroll
      for (int db = 0; db < 16; db++) {
        float v = Oacc[db][g] * inv;
        ushort hh, ll; split2(v, hh, ll);
        ahi[ro + db*16 + lr] = hh;
        alo[ro + db*16 + lr] = ll;
      }
    }
  }
}

// ---------------- K6b-A: linear attention S = Q.K^T (MFMA) ----------------
__global__ __launch_bounds__(256) void k_lin_qkt(const ushort* __restrict__ qkv,
                                                 ushort* __restrict__ Shi, ushort* __restrict__ Slo,
                                                 const int* __restrict__ row_base, const int* __restrict__ cnt) {
  int li = blockIdx.z;
  int z = (li >> 2) * 16 + (li & 3);
  int n = cnt[z];
  int q0 = blockIdx.y * 128, k0 = blockIdx.x * 128;
  if (q0 >= n || k0 >= n) return;
  int base = row_base[z];
  __shared__ ushort lds[2][128*32];
  int tid = threadIdx.x;
  int lane = tid & 63, w = tid >> 6;
  int wr = w >> 1, wc = w & 1;
  int lr = lane & 15, lk = lane >> 4;
  f32x4 acc[4][4] = {};
  int r0 = tid >> 2;
  int kc = (tid & 3) << 3;
  size_t a0 = (size_t)(base + min(q0 + r0, n - 1)) * 3072 + kc;
  size_t a1 = (size_t)(base + min(q0 + 64 + r0, n - 1)) * 3072 + kc;
  size_t b0 = (size_t)(base + min(k0 + r0, n - 1)) * 3072 + 1024 + kc;
  size_t b1 = (size_t)(base + min(k0 + 64 + r0, n - 1)) * 3072 + 1024 + kc;
  uint d0 = (uint)tid * 8, d1 = (uint)(256 + tid) * 8;
  for (int kb = 0; kb < 1024; kb += 32) {
    gload16(qkv + a0 + kb, &lds[0][d0]);
    gload16(qkv + a1 + kb, &lds[0][d1]);
    gload16(qkv + b0 + kb, &lds[1][d0]);
    gload16(qkv + b1 + kb, &lds[1][d1]);
    __syncthreads();
    short8 af[4], bf[4];
#pragma unroll
    for (int m = 0; m < 4; m++) af[m] = *(const short8*)&lds[0][(wr*64 + m*16 + lr)*32 + lk*8];
#pragma unroll
    for (int n2 = 0; n2 < 4; n2++) bf[n2] = *(const short8*)&lds[1][(wc*64 + n2*16 + lr)*32 + lk*8];
#pragma unroll
    for (int m = 0; m < 4; m++)
#pragma unroll
      for (int n2 = 0; n2 < 4; n2++)
        acc[m][n2] = __builtin_amdgcn_mfma_f32_16x16x32_bf16(af[m], bf[n2], acc[m][n2], 0, 0, 0);
    __syncthreads();
  }
#pragma unroll
  for (int n2 = 0; n2 < 4; n2++) {
    int col = k0 + wc*64 + n2*16 + lr;
#pragma unroll
    for (int m = 0; m < 4; m++) {
#pragma unroll
      for (int g = 0; g < 4; g++) {
        int row = q0 + wr*64 + m*16 + lk*4 + g;
        if (row < n) {
          float v = (col < n) ? acc[m][n2][g] : 0.f;
          ushort hh, ll; split2(v, hh, ll);
          size_t o = (size_t)li * (CAP*CAP) + (size_t)row * CAP + col;
          Shi[o] = hh; Slo[o] = ll;
        }
      }
    }
  }
}

// ---------------- K6b-B: linear attention O = (Shi+Slo).V * zq (MFMA) ----------------
__global__ __launch_bounds__(256) void k_lin_pv(const ushort* __restrict__ qkv,
                                                const ushort* __restrict__ Shi, const ushort* __restrict__ Slo,
                                                ushort* __restrict__ ahi, ushort* __restrict__ alo,
                                                const int* __restrict__ row_base, const int* __restrict__ cnt,
                                                const float* __restrict__ denomArr) {
  int li = blockIdx.y;
  int z = (li >> 2) * 16 + (li & 3);
  int n = cnt[z];
  int q0 = blockIdx.x * 64;
  if (q0 >= n) return;
  int base = row_base[z];
  __shared__ ushort Vt[256*40];
  int tid = threadIdx.x;
  int lane = tid & 63, w = tid >> 6;
  int lr = lane & 15, lk = lane >> 4;
  int ntile = (n + 31) >> 5;
  int k2 = tid >> 3, dg = tid & 7;
  int qrow = min(q0 + w*16 + lr, n - 1);
  const ushort* srowH = Shi + (size_t)li * (CAP*CAP) + (size_t)qrow * CAP;
  const ushort* srowL = Slo + (size_t)li * (CAP*CAP) + (size_t)qrow * CAP;
  for (int c = 0; c < 4; c++) {
    f32x4 Oacc[16];
#pragma unroll
    for (int db = 0; db < 16; db++) Oacc[db] = (f32x4){0.f, 0.f, 0.f, 0.f};
    for (int t = 0; t < ntile; t++) {
      __syncthreads();
      int krow = t*32 + k2;
      bool kval = krow < n;
      const ushort* vsrc = qkv + (size_t)(base + min(krow, n - 1))*3072 + 2048 + c*256 + dg*8;
#pragma unroll
      for (int tt = 0; tt < 4; tt++) {
        int dd = dg*8 + tt*64;
        short8 v = {0,0,0,0,0,0,0,0};
        if (kval) v = *(const short8*)(vsrc + tt*64);
#pragma unroll
        for (int j = 0; j < 8; j++) Vt[(dd + j)*40 + k2] = ((ushort*)&v)[j];
      }
      __syncthreads();
      short8 ph = *(const short8*)(srowH + t*32 + lk*8);
      short8 pl = *(const short8*)(srowL + t*32 + lk*8);
#pragma unroll
      for (int db = 0; db < 16; db++) {
        short8 vb = *(const short8*)(Vt + (db*16 + lr)*40 + lk*8);
        Oacc[db] = __builtin_amdgcn_mfma_f32_16x16x32_bf16(ph, vb, Oacc[db], 0, 0, 0);
        Oacc[db] = __builtin_amdgcn_mfma_f32_16x16x32_bf16(pl, vb, Oacc[db], 0, 0, 0);
      }
    }
#pragma unroll
    for (int g = 0; g < 4; g++) {
      int qr = q0 + w*16 + lk*4 + g;
      if (qr < n) {
        float zq = 1.f / (denomArr[base + qr] + 1e-6f);
        size_t ro = (size_t)(base + qr) * 1024 + c*256;
#pragma unroll
        for (int db = 0; db < 16; db++) {
          float v = Oacc[db][g] * zq;
          ushort hh, ll; split2(v, hh, ll);
          ahi[ro + db*16 + lr] = hh;
          alo[ro + db*16 + lr] = ll;
        }
      }
    }
  }
}

// ---------------- K11: weighted scatter ----------------
__global__ __launch_bounds__(256) void k_scatter(const float* __restrict__ o, const int* __restrict__ row_of,
                                                 const float* __restrict__ topw, float* __restrict__ out) {
  int t = blockIdx.x;
  float4 acc = make_float4(0.f, 0.f, 0.f, 0.f);
  for (int k = 0; k < TOPK; k++) {
    int row = row_of[t*TOPK + k];
    if (row >= 0) {
      float w = topw[t*TOPK + k];
      float4 v = ((const float4*)o)[(size_t)row * 256 + threadIdx.x];
      acc.x += w * v.x; acc.y += w * v.y; acc.z += w * v.z; acc.w += w * v.w;
    }
  }
  ((float4*)out)[(size_t)t * 256 + threadIdx.x] = acc;
}

extern "C" void kernel_launch(void* const* d_in, const int* in_sizes, int n_in,
                              void* d_out, int out_size, void* d_ws, size_t ws_size,
                              hipStream_t stream) {
  const float* x    = (const float*)d_in[0];
  const float* rw   = (const float*)d_in[1];
  const float* qkvw = (const float*)d_in[2];
  const float* qkvb = (const float*)d_in[3];
  const float* sww  = (const float*)d_in[4];
  const float* swb  = (const float*)d_in[5];
  const float* svw  = (const float*)d_in[6];
  const float* svb  = (const float*)d_in[7];
  const float* pjw  = (const float*)d_in[8];
  const float* pjb  = (const float*)d_in[9];
  float* out = (float*)d_out;

  char* ws = (char*)d_ws;
  const size_t MB = 1ull << 20;
  // Buffer lifetime map (no writer/reader overlap within any dispatch):
  //   xhi/xlo   [0,64)MB    : written by gather; read by qkv GEMM, xsum, denom.  DEAD after qkv GEMM.
  //   qkvB      [64,160)MB  : written by qkv GEMM; read by attn/lin.             DEAD after lin_pv.
  //   ahi/alo   [160,224)MB : written by attn + lin_pv; read by fused sw GEMM.
  //   Shi/Slo   [224,256)MB : written by lin_qkt; read by lin_pv.                DEAD after lin_pv.
  //   ghi/glo   [0,64)MB    : written by fused sw GEMM (xhi/xlo region);  read by sv GEMM.
  //   shi/slo   [224,288)MB : written by sv GEMM (Shi/Slo region);        read by proj GEMM.
  //   obuf      [64,128)MB  : written by proj GEMM (qkvB region);         read by scatter.
  ushort* xhi  = (ushort*)(ws + 0);
  ushort* xlo  = (ushort*)(ws + 32*MB);
  ushort* qkvB = (ushort*)(ws + 64*MB);
  ushort* ahi  = (ushort*)(ws + 160*MB);
  ushort* alo  = (ushort*)(ws + 192*MB);
  ushort* Shi  = (ushort*)(ws + 224*MB);
  ushort* Slo  = (ushort*)(ws + 240*MB);
  ushort* ghi  = (ushort*)(ws + 0);
  ushort* glo  = (ushort*)(ws + 32*MB);
  ushort* shi  = (ushort*)(ws + 224*MB);
  ushort* slo  = (ushort*)(ws + 256*MB);
  float*  obuf = (float*)(ws + 64*MB);
  char* sm = ws + 288*MB;
  size_t off = 0;
  auto alloc = [&](size_t bytes) { char* p = sm + off; off += (bytes + 255) & ~(size_t)255; return p; };
  int*   topi = (int*)alloc(T_TOK*TOPK*4);
  float* topw = (float*)alloc(T_TOK*TOPK*4);
  int*   pos  = (int*)alloc(T_TOK*TOPK*4);
  int*   rof  = (int*)alloc(T_TOK*TOPK*4);
  int*   craw = (int*)alloc(NEXP*TOPK*4);
  int*   cnt  = (int*)alloc(NEXP*TOPK*4);
  int*   rbase= (int*)alloc(NEXP*TOPK*4);
  int*   meta = (int*)alloc(256);
  float* xpart = (float*)alloc(32*8*1024*4);   // 1 MB partial column-sums
  float* ksum = (float*)alloc(32*1024*4);
  float* uvec = (float*)alloc(32*1024*4);
  float* cvec = (float*)alloc(32*4);
  float* denomArr = (float*)alloc(MAXROWS*4);
  float* upart = (float*)alloc(8*8*4*1024*4);

  k_router <<<T_TOK, 256, 0, stream>>>(x, rw, topi, topw);
  k_scan   <<<NEXP*TOPK, 256, 0, stream>>>(topi, pos, craw);
  k_offsets<<<1, 64, 0, stream>>>(craw, cnt, rbase, meta);
  k_gather <<<T_TOK*TOPK, 256, 0, stream>>>(x, topi, pos, rbase, rof, xhi, xlo);

  // exact f32 denominator bypass (linear experts); xsum parallelized over 8 row-chunks
  k_xsum  <<<dim3(32, 8), 256, 0, stream>>>(xhi, xlo, rbase, cnt, xpart);
  k_kmv1b <<<dim3(8, 32), 256, 0, stream>>>(qkvw, qkvb, xpart, cnt, ksum);
  k_kmv2b <<<dim3(8, 4, 8), 256, 0, stream>>>(qkvw, ksum, upart);
  k_kmv2r <<<dim3(32, 4), 256, 0, stream>>>(upart, uvec);
  k_cdot  <<<32, 256, 0, stream>>>(qkvb, ksum, cvec);
  k_denom <<<dim3(64, 32), 256, 0, stream>>>(xhi, xlo, uvec, cvec, rbase, cnt, denomArr);

  // qkv GEMM -> bf16 (R8-proven structure)
  dim3 gqkv(3072/128, 16, NEXP);
  k_mfma_gemm<1><<<gqkv, 256, 0, stream>>>(xhi, xlo, qkvw, qkvb, 3072, 0,
                                           nullptr, qkvB, nullptr, 3072, rbase, cnt, meta);

  dim3 ga(CAP/64, NH, NEXP*TOPK);
  k_attn_std<<<ga, 256, 0, stream>>>(qkvB, ahi, alo, rbase, cnt, meta);
  dim3 gq(CAP/128, CAP/128, 32);
  k_lin_qkt<<<gq, 256, 0, stream>>>(qkvB, Shi, Slo, rbase, cnt);
  dim3 gp(CAP/64, 32);
  k_lin_pv<<<gp, 256, 0, stream>>>(qkvB, Shi, Slo, ahi, alo, rbase, cnt, denomArr);

  // sw GEMM with fused SwiGLU epilogue -> g planes (xhi/xlo region; NOT aliasing ahi/alo)
  dim3 gsw(1024/64, 16, NEXP);
  k_mfma_gemm<3><<<gsw, 256, 0, stream>>>(ahi, alo, sww, swb, 2048, 0,
                                          nullptr, ghi, glo, 1024, rbase, cnt, meta);

  dim3 g1k(1024/128, 16, NEXP);
  k_mfma_gemm<2><<<g1k, 256, 0, stream>>>(ghi, glo, svw, svb, 1024, 0,
                                          nullptr, shi, slo, 1024, rbase, cnt, meta);
  k_mfma_gemm<0><<<g1k, 256, 0, stream>>>(shi, slo, pjw, pjb, 1024, 0,
                                          obuf, nullptr, nullptr, 1024, rbase, cnt, meta);

  k_scatter<<<T_TOK, 256, 0, stream>>>(obuf, rof, topw, out);
}